// Round 4
// baseline (1061.896 us; speedup 1.0000x reference)
//
#include <hip/hip_runtime.h>
#include <hip/hip_bf16.h>

// Problem constants
#define Bsz   16
#define Tn    2048
#define INC   80
#define Hc    512
#define Dc    512
#define NCODE 1024
#define BT    (Bsz * Tn)           // 32768
#define RECON_N (Bsz * Tn * INC)   // 2,621,440
#define MARGIN 0.03f               // approx-distance safety margin

typedef __attribute__((ext_vector_type(8))) short bf16x8;
typedef __attribute__((ext_vector_type(4))) float f32x4;
typedef __attribute__((ext_vector_type(4))) unsigned short u16x4;

// float -> bf16 (round-to-nearest-even), and back
static __device__ __forceinline__ unsigned short f2bf(float x) {
    unsigned u = __float_as_uint(x);
    u += 0x7FFF + ((u >> 16) & 1);
    return (unsigned short)(u >> 16);
}
static __device__ __forceinline__ float bf2f(unsigned short h) {
    return __uint_as_float((unsigned)h << 16);
}

// async global->LDS 16B copy (global_load_lds_dwordx4).
typedef const __attribute__((address_space(1))) unsigned int* gas_p;
typedef __attribute__((address_space(3))) unsigned int* las_p;
static __device__ __forceinline__ void async16(const void* g, const void* l) {
    __builtin_amdgcn_global_load_lds(
        (gas_p)(unsigned long long)g,
        (las_p)(unsigned int)(unsigned long long)l,
        16, 0, 0);
}

// ---------------------------------------------------------------------------
// code_norms: CN[j] = sum_d CB[j][d]^2
// ---------------------------------------------------------------------------
__global__ __launch_bounds__(64)
void code_norms(const float* __restrict__ CB, float* __restrict__ CN) {
    int j = blockIdx.x;
    int lane = threadIdx.x;
    const float4* row = (const float4*)(CB + (size_t)j * Dc);
    float s = 0.f;
    #pragma unroll
    for (int i = 0; i < 2; ++i) {
        float4 v = row[lane + i * 64];
        s = fmaf(v.x, v.x, s);
        s = fmaf(v.y, v.y, s);
        s = fmaf(v.z, v.z, s);
        s = fmaf(v.w, v.w, s);
    }
    #pragma unroll
    for (int off = 32; off > 0; off >>= 1) s += __shfl_down(s, off, 64);
    if (lane == 0) CN[j] = s;
}

// ---------------------------------------------------------------------------
// cb_transpose: CBt[d][j] = CB[j][d].  grid (NCODE/64, Dc/64), block 256
// ---------------------------------------------------------------------------
__global__ __launch_bounds__(256)
void cb_transpose(const float* __restrict__ CB, float* __restrict__ CBt) {
    const int j0 = blockIdx.x * 64;
    const int d0 = blockIdx.y * 64;
    __shared__ float ts[64][65];
    const int tid = threadIdx.x;
    for (int i = tid; i < 4096; i += 256) {
        int r = i >> 6, c = i & 63;
        ts[r][c] = CB[(size_t)(j0 + r) * Dc + d0 + c];
    }
    __syncthreads();
    for (int i = tid; i < 4096; i += 256) {
        int r = i >> 6, c = i & 63;
        CBt[(size_t)(d0 + r) * NCODE + j0 + c] = ts[c][r];
    }
}

// ---------------------------------------------------------------------------
// mels_transpose: MT[b][c][t] = M[b][t][c].  grid (Tn/64, Bsz), block 256
// ---------------------------------------------------------------------------
__global__ __launch_bounds__(256)
void mels_transpose(const float* __restrict__ M, float* __restrict__ MT) {
    const int t0 = blockIdx.x * 64;
    const int b  = blockIdx.y;
    __shared__ float ts[64][84];
    const int tid = threadIdx.x;
    #pragma unroll
    for (int it = 0; it < 5; ++it) {
        int i = tid + it * 256;            // < 1280
        int t = i / 20, c4 = i % 20;
        *(float4*)&ts[t][c4 * 4] =
            *(const float4*)&M[((size_t)b * Tn + t0 + t) * INC + c4 * 4];
    }
    __syncthreads();
    #pragma unroll
    for (int it = 0; it < 20; ++it) {
        int i = tid + it * 256;            // < 5120
        int c = i >> 6, t = i & 63;
        MT[((size_t)b * INC + c) * Tn + t0 + t] = ts[t][c];
    }
}

// ---------------------------------------------------------------------------
// wt_transpose: Wt[(c*3+k)*Cout + o] = W[(o*Cin + c)*3 + k]
// ---------------------------------------------------------------------------
__global__ __launch_bounds__(256)
void wt_transpose(const float* __restrict__ W, float* __restrict__ Wt,
                  int Cin, int Cout) {
    const int o0 = blockIdx.x * 64;
    const int c0 = blockIdx.y * 16;
    __shared__ float ts[48][65];
    const int tid = threadIdx.x;
    for (int i = tid; i < 64 * 48; i += 256) {
        int o = i / 48, ck = i % 48;
        int oo = o0 + o;
        float v = 0.f;
        if (oo < Cout) v = W[(size_t)oo * Cin * 3 + c0 * 3 + ck];
        ts[ck][o] = v;
    }
    __syncthreads();
    for (int i = tid; i < 48 * 64; i += 256) {
        int o = i & 63, ck = i >> 6;
        int oo = o0 + o;
        if (oo < Cout) Wt[(size_t)(c0 * 3 + ck) * Cout + oo] = ts[ck][o];
    }
}

// ---------------------------------------------------------------------------
// wsplit: enc_w2 [o][c][k] fp32 -> Whl interleaved bf16
// [k][o][16 groups][hi32|lo32] so a lane's Ah/Al pair shares one cache line.
// ---------------------------------------------------------------------------
__global__ __launch_bounds__(256)
void wsplit(const float* __restrict__ W, unsigned short* __restrict__ Whl) {
    int o = blockIdx.x, k = blockIdx.y;
    #pragma unroll
    for (int it = 0; it < 2; ++it) {
        int c = threadIdx.x + it * 256;
        float v = W[((size_t)o * Hc + c) * 3 + k];
        unsigned short h = f2bf(v);
        size_t base = ((size_t)(k * Hc + o) * 16 + (c >> 5)) * 64 + (c & 31);
        Whl[base] = h;
        Whl[base + 32] = f2bf(v - bf2f(h));
    }
}

// ---------------------------------------------------------------------------
// wsplit80: dec_w2 [o][c][k] fp32 -> Wh2 [k][o][c] bf16 (hi only).
// ---------------------------------------------------------------------------
__global__ __launch_bounds__(256)
void wsplit80(const float* __restrict__ W, unsigned short* __restrict__ Wh) {
    int o = blockIdx.x, k = blockIdx.y;
    #pragma unroll
    for (int it = 0; it < 2; ++it) {
        int c = threadIdx.x + it * 256;
        Wh[((size_t)k * INC + o) * Hc + c] = f2bf(W[((size_t)o * Hc + c) * 3 + k]);
    }
}

// ---------------------------------------------------------------------------
// cbsplit: codebook [j][d] fp32 -> CBhl interleaved [j][16][hi32|lo32].
// ---------------------------------------------------------------------------
__global__ __launch_bounds__(256)
void cbsplit(const float* __restrict__ CB, unsigned short* __restrict__ CBhl) {
    int j = blockIdx.x;
    #pragma unroll
    for (int it = 0; it < 2; ++it) {
        int d = threadIdx.x + it * 256;
        float v = CB[(size_t)j * Dc + d];
        unsigned short h = f2bf(v);
        size_t base = ((size_t)j * 16 + (d >> 5)) * 64 + (d & 31);
        CBhl[base] = h;
        CBhl[base + 32] = f2bf(v - bf2f(h));
    }
}

// ---------------------------------------------------------------------------
// conv_enc1: melsT [B,80,T] -> y1hl interleaved bf16 hi/lo, K=3, ReLU.
// ---------------------------------------------------------------------------
__global__ __launch_bounds__(256)
void conv_enc1(const float* __restrict__ X, const float* __restrict__ Wt,
               const float* __restrict__ bias, unsigned short* __restrict__ Yhl) {
    const int t0 = blockIdx.x * 64;
    const int o0 = blockIdx.y * 128;
    const int b  = blockIdx.z;
    union SharedU {
        struct { float Xs[16][72]; float Ws[48][132]; } a;
        float Ys[128][69];
    };
    __shared__ __align__(16) SharedU su;
    float (&Xs)[16][72]  = su.a.Xs;
    float (&Ws)[48][132] = su.a.Ws;
    const int tid = threadIdx.x;
    const int tx = tid & 15, ty = tid >> 4;
    float acc[8][4] = {};
    const float* Xb = X + (size_t)b * INC * Tn;

    for (int c0 = 0; c0 < INC; c0 += 16) {
        for (int i = tid; i < 16 * 66; i += 256) {
            int cc = i / 66, tt = i % 66;
            int t = t0 + tt - 1;
            float v = 0.f;
            if (t >= 0 && t < Tn) v = Xb[(size_t)(c0 + cc) * Tn + t];
            Xs[cc][tt] = v;
        }
        for (int i = tid; i < 48 * 128; i += 256) {
            int o = i & 127, ck = i >> 7;
            Ws[ck][o] = Wt[(size_t)(c0 * 3 + ck) * Hc + o0 + o];
        }
        __syncthreads();
        #pragma unroll
        for (int cc = 0; cc < 16; ++cc) {
            float4 xa = *(const float4*)&Xs[cc][tx * 4];
            float2 xb2 = *(const float2*)&Xs[cc][tx * 4 + 4];
            float xv[6] = {xa.x, xa.y, xa.z, xa.w, xb2.x, xb2.y};
            #pragma unroll
            for (int k = 0; k < 3; ++k) {
                float4 wa = *(const float4*)&Ws[cc * 3 + k][ty * 4];
                float4 wb = *(const float4*)&Ws[cc * 3 + k][64 + ty * 4];
                float wv[8] = {wa.x, wa.y, wa.z, wa.w, wb.x, wb.y, wb.z, wb.w};
                #pragma unroll
                for (int i8 = 0; i8 < 8; ++i8)
                    #pragma unroll
                    for (int j = 0; j < 4; ++j)
                        acc[i8][j] = fmaf(wv[i8], xv[k + j], acc[i8][j]);
            }
        }
        __syncthreads();
    }
    // epilogue phase 1: relu(acc+bias) -> Ys[o_local][t_local]
    #pragma unroll
    for (int og = 0; og < 2; ++og)
        #pragma unroll
        for (int oi = 0; oi < 4; ++oi) {
            int ol = og * 64 + ty * 4 + oi;
            float bv = bias[o0 + ol];
            const int i8 = og * 4 + oi;
            #pragma unroll
            for (int j = 0; j < 4; ++j)
                su.Ys[ol][tx * 4 + j] = fmaxf(acc[i8][j] + bv, 0.f);
        }
    __syncthreads();
    // epilogue phase 2: cooperative interleaved hi/lo write (coalesced 8B)
    #pragma unroll
    for (int it = 0; it < 8; ++it) {
        int i = tid + it * 256;            // 2048 = 32 o-quads x 64 t
        int oq = i & 31, t = i >> 5;
        int o4 = o0 + oq * 4;
        u16x4 h, l;
        #pragma unroll
        for (int r = 0; r < 4; ++r) {
            float v = su.Ys[oq * 4 + r][t];
            unsigned short hh = f2bf(v);
            h[r] = hh;
            l[r] = f2bf(v - bf2f(hh));
        }
        size_t base = ((size_t)(b * (Tn + 2) + 1 + t0 + t) * 16 + (o4 >> 5)) * 64
                      + (o4 & 31);
        *(u16x4*)(Yhl + base) = h;
        *(u16x4*)(Yhl + base + 32) = l;
    }
}

// ---------------------------------------------------------------------------
// zero_guards: zero padded guard rows (t=-1 and t=Tn) of interleaved buffer.
// ---------------------------------------------------------------------------
__global__ __launch_bounds__(256)
void zero_guards(unsigned short* __restrict__ Yhl) {
    const int b = blockIdx.x;
    u16x4 z = {0, 0, 0, 0};
    size_t r0 = (size_t)(b * (Tn + 2)) * 1024;
    size_t r1 = (size_t)(b * (Tn + 2) + Tn + 1) * 1024;
    *(u16x4*)(Yhl + r0 + threadIdx.x * 4) = z;
    *(u16x4*)(Yhl + r1 + threadIdx.x * 4) = z;
}

// ---------------------------------------------------------------------------
// split_t: X fp32 [B][512][Tn] -> Yhl interleaved bf16 (z -> Zt).
// grid (Tn/64, 512/64, B), block 256.
// ---------------------------------------------------------------------------
__global__ __launch_bounds__(256)
void split_t(const float* __restrict__ X, unsigned short* __restrict__ Yhl,
             int rowStride, int rowOff) {
    const int t0 = blockIdx.x * 64;
    const int c0 = blockIdx.y * 64;
    const int b  = blockIdx.z;
    __shared__ __align__(16) float ts[64][68];
    const int tid = threadIdx.x;
    #pragma unroll
    for (int it = 0; it < 4; ++it) {
        int i = tid + it * 256;            // < 1024
        int cc = i >> 4, t4 = i & 15;
        float4 v = *(const float4*)&X[((size_t)b * Hc + c0 + cc) * Tn + t0 + t4 * 4];
        ts[t4 * 4 + 0][cc] = v.x;
        ts[t4 * 4 + 1][cc] = v.y;
        ts[t4 * 4 + 2][cc] = v.z;
        ts[t4 * 4 + 3][cc] = v.w;
    }
    __syncthreads();
    #pragma unroll
    for (int it = 0; it < 4; ++it) {
        int i = tid + it * 256;            // < 1024
        int t = i >> 4, c4 = i & 15;
        int c = c0 + c4 * 4;
        float4 v = *(const float4*)&ts[t][c4 * 4];
        float va[4] = {v.x, v.y, v.z, v.w};
        u16x4 h, l;
        #pragma unroll
        for (int r = 0; r < 4; ++r) {
            unsigned short hh = f2bf(va[r]);
            h[r] = hh;
            l[r] = f2bf(va[r] - bf2f(hh));
        }
        size_t base = ((size_t)(b * rowStride + rowOff + t0 + t) * 16 + (c >> 5)) * 64
                      + (c & 31);
        *(u16x4*)(Yhl + base) = h;
        *(u16x4*)(Yhl + base + 32) = l;
    }
}

// ---------------------------------------------------------------------------
// conv_mid_mfma: implicit GEMM, async16 staging, XOR-swizzled LDS, merged
// hi/lo weight lines, setprio. t-tile 64 (LDS 18.4KB, acc 32 VGPR) for
// ~2x blocks/CU -> latency hiding via independent barrier groups.
// grid (Tn/64, Hc/128, B), block 256. Writes exact fp32 z.
// ---------------------------------------------------------------------------
__global__ __launch_bounds__(256)
void conv_mid_mfma(const unsigned short* __restrict__ Xhl,
                   const unsigned short* __restrict__ Whl,
                   const float* __restrict__ bias,
                   float* __restrict__ Y) {
    const int t0 = blockIdx.x * 64;
    const int o0 = blockIdx.y * 128;
    const int b  = blockIdx.z;
    __shared__ __align__(16) unsigned short XL[2][72 * 64];  // 2 x 9216 B
    const int tid  = threadIdx.x;
    const int lane = tid & 63;
    const int wave = tid >> 6;
    const int wm = wave >> 1, wn = wave & 1;
    const int m16 = lane & 15;
    const int q = lane >> 4;
    const int lrow = lane >> 3;
    const int lchk = (lane & 7) ^ lrow;
    const unsigned short* Xb = Xhl + ((size_t)b * (Tn + 2) + t0) * 1024
                               + (size_t)lrow * 1024 + lchk * 8;

    f32x4 acc[4][2];
    #pragma unroll
    for (int mt = 0; mt < 4; ++mt)
        #pragma unroll
        for (int nt = 0; nt < 2; ++nt)
            acc[mt][nt] = (f32x4){0.f, 0.f, 0.f, 0.f};

    // prologue: stage group 0 (9 instrs x 8 rows x 128B = rows 0..71)
    #pragma unroll
    for (int i = 0; i < 3; ++i) {
        int ii = wave + i * 4;
        if (ii < 9)
            async16(Xb + (size_t)ii * 8192, &XL[0][ii * 512]);
    }

    for (int c0 = 0; c0 < Hc; c0 += 32) {
        const int buf = (c0 >> 5) & 1;
        __syncthreads();   // drains vmcnt(0): buf is ready, buf^1 free
        if (c0 + 32 < Hc) {
            const unsigned short* src = Xb + (size_t)((c0 >> 5) + 1) * 64;
            #pragma unroll
            for (int i = 0; i < 3; ++i) {
                int ii = wave + i * 4;
                if (ii < 9)
                    async16(src + (size_t)ii * 8192, &XL[buf ^ 1][ii * 512]);
            }
        }
        #pragma unroll
        for (int k = 0; k < 3; ++k) {
            bf16x8 Ah[4], Al[4];
            #pragma unroll
            for (int mt = 0; mt < 4; ++mt) {
                int o = o0 + wm * 64 + mt * 16 + m16;
                size_t base = ((size_t)(k * Hc + o) * 16 + (c0 >> 5)) * 64 + q * 8;
                Ah[mt] = *(const bf16x8*)(Whl + base);
                Al[mt] = *(const bf16x8*)(Whl + base + 32);
            }
            #pragma unroll
            for (int nt = 0; nt < 2; ++nt) {
                int row = wn * 32 + nt * 16 + m16 + k;   // 0..65
                const unsigned short* rp = &XL[buf][row * 64];
                int ph = (q ^ (row & 7)) * 8;            // hi phys chunk
                union { bf16x8 v; uint4 u; } bh, bl;
                bh.u = *(const uint4*)(rp + ph);
                bl.u = *(const uint4*)(rp + (ph ^ 32));  // lo = hi slot ^ 4
                __builtin_amdgcn_s_setprio(1);
                #pragma unroll
                for (int mt = 0; mt < 4; ++mt)
                    acc[mt][nt] = __builtin_amdgcn_mfma_f32_16x16x32_bf16(
                        Ah[mt], bh.v, acc[mt][nt], 0, 0, 0);
                #pragma unroll
                for (int mt = 0; mt < 4; ++mt)
                    acc[mt][nt] = __builtin_amdgcn_mfma_f32_16x16x32_bf16(
                        Al[mt], bh.v, acc[mt][nt], 0, 0, 0);
                #pragma unroll
                for (int mt = 0; mt < 4; ++mt)
                    acc[mt][nt] = __builtin_amdgcn_mfma_f32_16x16x32_bf16(
                        Ah[mt], bl.v, acc[mt][nt], 0, 0, 0);
                __builtin_amdgcn_s_setprio(0);
            }
        }
    }
    // epilogue: bias + exact fp32 write [B,512,T]
    float* Yb = Y + (size_t)b * Hc * Tn;
    #pragma unroll
    for (int mt = 0; mt < 4; ++mt) {
        int ob = o0 + wm * 64 + mt * 16 + q * 4;
        float4 bq = *(const float4*)&bias[ob];
        float bqa[4] = {bq.x, bq.y, bq.z, bq.w};
        #pragma unroll
        for (int nt = 0; nt < 2; ++nt) {
            int t = t0 + wn * 32 + nt * 16 + m16;
            #pragma unroll
            for (int r = 0; r < 4; ++r)
                Yb[(size_t)(ob + r) * Tn + t] = acc[mt][nt][r] + bqa[r];
        }
    }
}

// ---------------------------------------------------------------------------
// dec2_mfma: recon = conv(y3, dec_w2) + b, single-bf16 implicit GEMM.
// ---------------------------------------------------------------------------
__global__ __launch_bounds__(256)
void dec2_mfma(const float* __restrict__ X,
               const unsigned short* __restrict__ Wh2,
               const float* __restrict__ bias, float* __restrict__ OUT) {
    const int t0 = blockIdx.x * 128;
    const int b  = blockIdx.z;
    __shared__ unsigned short Xs[2][130 * 36];
    const int tid = threadIdx.x;
    const int lane = tid & 63;
    const int wn = tid >> 6;           // wave = t-quadrant (32 t each)
    const int m16 = lane & 15;
    const int q = lane >> 4;
    const float* Xb = X + (size_t)b * Hc * Tn;

    f32x4 acc[5][2];
    #pragma unroll
    for (int mt = 0; mt < 5; ++mt)
        #pragma unroll
        for (int nt = 0; nt < 2; ++nt)
            acc[mt][nt] = (f32x4){0.f, 0.f, 0.f, 0.f};

    float xr[17];
    #pragma unroll
    for (int it = 0; it < 17; ++it) {
        int f = tid + it * 256;
        if (it < 16 || tid < 64) {
            int cc = f / 130, tt = f - cc * 130;
            int t = t0 + tt - 1;
            xr[it] = (t >= 0 && t < Tn) ? Xb[(size_t)cc * Tn + t] : 0.f;
        }
    }

    for (int c0 = 0; c0 < Hc; c0 += 32) {
        const int buf = (c0 >> 5) & 1;
        #pragma unroll
        for (int it = 0; it < 17; ++it) {
            int f = tid + it * 256;
            if (it < 16 || tid < 64) {
                int cc = f / 130, tt = f - cc * 130;
                Xs[buf][tt * 36 + cc] = f2bf(xr[it]);
            }
        }
        __syncthreads();
        if (c0 + 32 < Hc) {
            const float* Xc = Xb + (size_t)(c0 + 32) * Tn;
            #pragma unroll
            for (int it = 0; it < 17; ++it) {
                int f = tid + it * 256;
                if (it < 16 || tid < 64) {
                    int cc = f / 130, tt = f - cc * 130;
                    int t = t0 + tt - 1;
                    xr[it] = (t >= 0 && t < Tn) ? Xc[(size_t)cc * Tn + t] : 0.f;
                }
            }
        }
        #pragma unroll
        for (int k = 0; k < 3; ++k) {
            bf16x8 Ah[5];
            #pragma unroll
            for (int mt = 0; mt < 5; ++mt) {
                int o = mt * 16 + m16;
                Ah[mt] = *(const bf16x8*)(Wh2 + ((size_t)(k * INC + o)) * Hc + c0 + q * 8);
            }
            #pragma unroll
            for (int nt = 0; nt < 2; ++nt) {
                int tt = wn * 32 + nt * 16 + m16 + k;
                union { bf16x8 v; uint2 h[2]; } bh;
                const unsigned short* ph = Xs[buf] + tt * 36 + q * 8;
                bh.h[0] = *(const uint2*)ph; bh.h[1] = *(const uint2*)(ph + 4);
                #pragma unroll
                for (int mt = 0; mt < 5; ++mt)
                    acc[mt][nt] = __builtin_amdgcn_mfma_f32_16x16x32_bf16(
                        Ah[mt], bh.v, acc[mt][nt], 0, 0, 0);
            }
        }
    }
    #pragma unroll
    for (int mt = 0; mt < 5; ++mt) {
        float4 bq = *(const float4*)&bias[mt * 16 + q * 4];
        #pragma unroll
        for (int nt = 0; nt < 2; ++nt) {
            int t = t0 + wn * 32 + nt * 16 + m16;
            float4 r;
            r.x = acc[mt][nt][0] + bq.x;
            r.y = acc[mt][nt][1] + bq.y;
            r.z = acc[mt][nt][2] + bq.z;
            r.w = acc[mt][nt][3] + bq.w;
            *(float4*)(OUT + ((size_t)b * Tn + t) * INC + mt * 16 + q * 4) = r;
        }
    }
}

// ---------------------------------------------------------------------------
// vq_mfma: approx distances via 3xbf16 MFMA GEMM reading pre-split Zt.
// t-tile 64 (LDS 16KB, acc 32 VGPR) for higher blocks/CU.
// grid (BT/64, NCODE/128), block 256.
// ---------------------------------------------------------------------------
__global__ __launch_bounds__(256)
void vq_mfma(const unsigned short* __restrict__ Zt,
             const unsigned short* __restrict__ CBhl,
             const float* __restrict__ CN,
             float* __restrict__ candv, int* __restrict__ candi,
             float* __restrict__ cand2v) {
    const int nb = blockIdx.x;
    const int jb = blockIdx.y;
    const int b  = nb >> 5;
    const int t0 = (nb & 31) * 64;
    const int jbase = jb * 128;
    __shared__ __align__(16) unsigned char pool[16384];
    unsigned short* XL0 = (unsigned short*)pool;            // 8192 B
    unsigned short* XL1 = (unsigned short*)(pool + 8192);   // 8192 B
    float* RV = (float*)pool;                                // reused after
    int*   RI = (int*)(pool + 2048);
    float* R2 = (float*)(pool + 4096);

    const int tid = threadIdx.x;
    const int lane = tid & 63;
    const int wave = tid >> 6;
    const int wm = wave >> 1, wn = wave & 1;
    const int m16 = lane & 15;
    const int q = lane >> 4;
    const int lrow = lane >> 3;
    const int lchk = (lane & 7) ^ lrow;
    const unsigned short* Zb = Zt + (size_t)(b * Tn + t0) * 1024
                               + (size_t)lrow * 1024 + lchk * 8;

    f32x4 acc[4][2];
    #pragma unroll
    for (int mt = 0; mt < 4; ++mt)
        #pragma unroll
        for (int nt = 0; nt < 2; ++nt)
            acc[mt][nt] = (f32x4){0.f, 0.f, 0.f, 0.f};

    // prologue: stage group 0 (8 instrs x 8 rows x 128B = rows 0..63)
    #pragma unroll
    for (int i = 0; i < 2; ++i) {
        int ii = wave + i * 4;
        async16(Zb + (size_t)ii * 8192, XL0 + ii * 512);
    }

    for (int d0 = 0; d0 < Dc; d0 += 32) {
        const int buf = (d0 >> 5) & 1;
        unsigned short* XL = buf ? XL1 : XL0;
        __syncthreads();
        if (d0 + 32 < Dc) {
            unsigned short* XN = buf ? XL0 : XL1;
            const unsigned short* src = Zb + (size_t)((d0 >> 5) + 1) * 64;
            #pragma unroll
            for (int i = 0; i < 2; ++i) {
                int ii = wave + i * 4;
                async16(src + (size_t)ii * 8192, XN + ii * 512);
            }
        }
        bf16x8 Ah[4], Al[4];
        #pragma unroll
        for (int mt = 0; mt < 4; ++mt) {
            int j = jbase + wm * 64 + mt * 16 + m16;
            size_t base = ((size_t)j * 16 + (d0 >> 5)) * 64 + q * 8;
            Ah[mt] = *(const bf16x8*)(CBhl + base);
            Al[mt] = *(const bf16x8*)(CBhl + base + 32);
        }
        #pragma unroll
        for (int nt = 0; nt < 2; ++nt) {
            int row = wn * 32 + nt * 16 + m16;
            const unsigned short* rp = XL + row * 64;
            int ph = (q ^ (row & 7)) * 8;
            union { bf16x8 v; uint4 u; } bh, bl;
            bh.u = *(const uint4*)(rp + ph);
            bl.u = *(const uint4*)(rp + (ph ^ 32));
            __builtin_amdgcn_s_setprio(1);
            #pragma unroll
            for (int mt = 0; mt < 4; ++mt)
                acc[mt][nt] = __builtin_amdgcn_mfma_f32_16x16x32_bf16(
                    Ah[mt], bh.v, acc[mt][nt], 0, 0, 0);
            #pragma unroll
            for (int mt = 0; mt < 4; ++mt)
                acc[mt][nt] = __builtin_amdgcn_mfma_f32_16x16x32_bf16(
                    Al[mt], bh.v, acc[mt][nt], 0, 0, 0);
            #pragma unroll
            for (int mt = 0; mt < 4; ++mt)
                acc[mt][nt] = __builtin_amdgcn_mfma_f32_16x16x32_bf16(
                    Ah[mt], bl.v, acc[mt][nt], 0, 0, 0);
            __builtin_amdgcn_s_setprio(0);
        }
    }
    __syncthreads();

    float cn4[4][4];
    #pragma unroll
    for (int mt = 0; mt < 4; ++mt) {
        float4 c = *(const float4*)&CN[jbase + wm * 64 + mt * 16 + q * 4];
        cn4[mt][0] = c.x; cn4[mt][1] = c.y; cn4[mt][2] = c.z; cn4[mt][3] = c.w;
    }
    #pragma unroll
    for (int nt = 0; nt < 2; ++nt) {
        int t = wn * 32 + nt * 16 + m16;
        float v1 = 1e30f, v2 = 1e30f;
        int i1 = 0;
        #pragma unroll
        for (int mt = 0; mt < 4; ++mt)
            #pragma unroll
            for (int r = 0; r < 4; ++r) {
                float d = fmaf(-2.f, acc[mt][nt][r], cn4[mt][r]);
                int j = jbase + wm * 64 + mt * 16 + q * 4 + r;
                if (d < v1 || (d == v1 && j < i1)) { v2 = v1; v1 = d; i1 = j; }
                else if (d < v2) v2 = d;
            }
        int slot = wm * 4 + q;
        RV[t * 8 + slot] = v1;
        RI[t * 8 + slot] = i1;
        R2[t * 8 + slot] = v2;
    }
    __syncthreads();
    if (tid < 64) {
        int t = tid;
        float v1 = RV[t * 8], v2 = R2[t * 8];
        int i1 = RI[t * 8];
        #pragma unroll
        for (int s = 1; s < 8; ++s) {
            float a1 = RV[t * 8 + s], a2 = R2[t * 8 + s];
            int ai = RI[t * 8 + s];
            if (a1 < v1 || (a1 == v1 && ai < i1)) {
                v2 = fminf(v1, a2); v1 = a1; i1 = ai;
            } else {
                v2 = fminf(v2, a1);
            }
        }
        int n = b * Tn + t0 + t;
        candv[(size_t)jb * BT + n] = v1;
        candi[(size_t)jb * BT + n] = i1;
        cand2v[(size_t)jb * BT + n] = v2;
    }
}

// ---------------------------------------------------------------------------
// vq_reduce2: merge 8 j-block candidates; flag near-ties for exact rescore.
// ---------------------------------------------------------------------------
__global__ __launch_bounds__(256)
void vq_reduce2(const float* __restrict__ candv, const int* __restrict__ candi,
                const float* __restrict__ cand2v, int* __restrict__ idxI,
                float* __restrict__ idxf, int* __restrict__ flagn,
                int* __restrict__ flaglist) {
    int n = blockIdx.x * 256 + threadIdx.x;
    float v1 = candv[n], v2 = cand2v[n];
    int i1 = candi[n];
    #pragma unroll
    for (int jq = 1; jq < 8; ++jq) {
        float a1 = candv[(size_t)jq * BT + n];
        float a2 = cand2v[(size_t)jq * BT + n];
        int ai = candi[(size_t)jq * BT + n];
        if (a1 < v1 || (a1 == v1 && ai < i1)) {
            v2 = fminf(v1, a2); v1 = a1; i1 = ai;
        } else {
            v2 = fminf(v2, a1);
        }
    }
    idxI[n] = i1;
    idxf[n] = (float)i1;
    if (v2 - v1 < MARGIN) {
        int s = atomicAdd(flagn, 1);
        flaglist[s] = n;
    }
}

// ---------------------------------------------------------------------------
// vq_rescue: exact fp32 re-score of flagged positions over all 1024 codes.
// ---------------------------------------------------------------------------
__global__ __launch_bounds__(256)
void vq_rescue(const int* __restrict__ flagn, const int* __restrict__ flaglist,
               const float* __restrict__ Z, const float* __restrict__ CB,
               const float* __restrict__ CN, int* __restrict__ idxI,
               float* __restrict__ idxf) {
    __shared__ float zs[512];
    __shared__ float rvv[256];
    __shared__ int   rii[256];
    const int nf = *flagn;
    for (int f = blockIdx.x; f < nf; f += gridDim.x) {
        int n = flaglist[f];
        int b = n / Tn, t = n - b * Tn;
        __syncthreads();
        #pragma unroll
        for (int it = 0; it < 2; ++it) {
            int d = threadIdx.x + it * 256;
            zs[d] = Z[((size_t)b * Dc + d) * Tn + t];
        }
        __syncthreads();
        float bv = 1e30f;
        int bi = 0;
        #pragma unroll
        for (int jj = 0; jj < 4; ++jj) {
            int j = threadIdx.x * 4 + jj;
            const float* cr = CB + (size_t)j * Dc;
            float dot = 0.f;
            for (int d = 0; d < Dc; ++d) dot = fmaf(zs[d], cr[d], dot);
            float dist = fmaf(-2.f, dot, CN[j]);
            if (dist < bv || (dist == bv && j < bi)) { bv = dist; bi = j; }
        }
        rvv[threadIdx.x] = bv;
        rii[threadIdx.x] = bi;
        __syncthreads();
        for (int off = 128; off > 0; off >>= 1) {
            if (threadIdx.x < off) {
                float ov = rvv[threadIdx.x + off];
                int oi = rii[threadIdx.x + off];
                if (ov < rvv[threadIdx.x] ||
                    (ov == rvv[threadIdx.x] && oi < rii[threadIdx.x])) {
                    rvv[threadIdx.x] = ov; rii[threadIdx.x] = oi;
                }
            }
            __syncthreads();
        }
        if (threadIdx.x == 0) {
            idxI[n] = rii[0];
            idxf[n] = (float)rii[0];
        }
    }
}

// ---------------------------------------------------------------------------
// gemm_g: G[j][kk*512+o] = sum_c CB[j][c] * dec_w1[o][c][kk].
// ---------------------------------------------------------------------------
__global__ __launch_bounds__(256)
void gemm_g(const float* __restrict__ CBt, const float* __restrict__ Wt,
            float* __restrict__ G) {
    const int j0 = blockIdx.x * 64;
    const int kk = blockIdx.y >> 2;
    const int o0 = (blockIdx.y & 3) * 128;
    __shared__ __align__(16) float As[16][68];
    __shared__ __align__(16) float Bs[16][132];
    const int tid = threadIdx.x;
    const int tx = tid & 15, ty = tid >> 4;
    float acc[4][8] = {};

    for (int c0 = 0; c0 < Dc; c0 += 16) {
        {
            int cc = tid >> 4, j4 = tid & 15;
            *(float4*)&As[cc][j4 * 4] =
                *(const float4*)&CBt[(size_t)(c0 + cc) * NCODE + j0 + j4 * 4];
        }
        #pragma unroll
        for (int it = 0; it < 2; ++it) {
            int i = tid + it * 256;
            int cc = i >> 5, o4 = i & 31;
            *(float4*)&Bs[cc][o4 * 4] =
                *(const float4*)&Wt[(size_t)((c0 + cc) * 3 + kk) * Hc + o0 + o4 * 4];
        }
        __syncthreads();
        #pragma unroll
        for (int cc = 0; cc < 16; ++cc) {
            float4 a = *(const float4*)&As[cc][tx * 4];
            float av[4] = {a.x, a.y, a.z, a.w};
            float4 b0 = *(const float4*)&Bs[cc][ty * 4];
            float4 b1 = *(const float4*)&Bs[cc][64 + ty * 4];
            float bv[8] = {b0.x, b0.y, b0.z, b0.w, b1.x, b1.y, b1.z, b1.w};
            #pragma unroll
            for (int jj = 0; jj < 4; ++jj)
                #pragma unroll
                for (int oo = 0; oo < 8; ++oo)
                    acc[jj][oo] = fmaf(av[jj], bv[oo], acc[jj][oo]);
        }
        __syncthreads();
    }
    #pragma unroll
    for (int jj = 0; jj < 4; ++jj) {
        int j = j0 + tx * 4 + jj;
        float* gp = G + (size_t)j * 1536 + kk * 512 + o0;
        *(float4*)(gp + ty * 4) = *(float4*)&acc[jj][0];
        *(float4*)(gp + 64 + ty * 4) = *(float4*)&acc[jj][4];
    }
}

// ---------------------------------------------------------------------------
// dec_y3: y3[b][o][t] = relu(b1[o] + sum_kk G[idx[b][t+kk-1]][kk*512+o]).
// ---------------------------------------------------------------------------
__global__ __launch_bounds__(256)
void dec_y3(const int* __restrict__ idx, const float* __restrict__ G,
            const float* __restrict__ bias, float* __restrict__ Y) {
    const int t0 = blockIdx.x * 64;
    const int o0 = blockIdx.y * 128;
    const int b  = blockIdx.z;
    const int tid = threadIdx.x;
    __shared__ int sidx[66];
    __shared__ __align__(16) float Ys[128][68];

    if (tid < 66) {
        int t = t0 + tid - 1;
        sidx[tid] = (t >= 0 && t < Tn) ? idx[b * Tn + t] : -1;
    }
    __syncthreads();

    const int o = tid & 127;
    const int half = tid >> 7;
    float acc[32] = {};
    #pragma unroll
    for (int kk = 0; kk < 3; ++kk) {
        const float* Gk = G + (size_t)kk * 512 + o0 + o;
        #pragma unroll
        for (int k = 0; k < 32; ++k) {
            int j = sidx[half + 2 * k + kk];
            if (j >= 0) acc[k] += Gk[(size_t)j * 1536];
        }
    }
    float bv = bias[o0 + o];
    #pragma unroll
    for (int k = 0; k < 32; ++k)
        Ys[o][half + 2 * k] = fmaxf(acc[k] + bv, 0.f);
    __syncthreads();

    float* Yb = Y + (size_t)b * Hc * Tn + t0;
    #pragma unroll
    for (int it = 0; it < 8; ++it) {
        int i = tid + it * 256;
        int t4 = i & 15, oo = i >> 4;
        *(float4*)&Yb[(size_t)(o0 + oo) * Tn + t4 * 4] =
            *(const float4*)&Ys[oo][t4 * 4];
    }
}

// ---------------------------------------------------------------------------
extern "C" void kernel_launch(void* const* d_in, const int* in_sizes, int n_in,
                              void* d_out, int out_size, void* d_ws, size_t ws_size,
                              hipStream_t stream) {
    const float* mels    = (const float*)d_in[0];
    const float* enc_w1  = (const float*)d_in[1];
    const float* enc_b1  = (const float*)d_in[2];
    const float* enc_w2  = (const float*)d_in[3];
    const float* enc_b2  = (const float*)d_in[4];
    const float* codebook= (const float*)d_in[5];
    const float* dec_w1  = (const float*)d_in[6];
    const float* dec_b1  = (const float*)d_in[7];
    const float* dec_w2  = (const float*)d_in[8];
    const float* dec_b2  = (const float*)d_in[9];

    float* out = (float*)d_out;
    float* recon = out;                 // [B,T,80]
    float* idxf  = out + RECON_N;       // [B,T] as float

    const size_t ACT = (size_t)Bsz * Hc * Tn;          // 16,777,216 floats
    const size_t Y1HL_U = (size_t)Bsz * (Tn + 2) * 1024 + 16384; // ushorts+slack
    const size_t R2F = Y1HL_U / 2;                      // floats

    // Region R1 (64 MB): z fp32 (conv_mid out, rescue reads) -> later y3
    float* zf = (float*)d_ws;
    float* y3 = (float*)d_ws;
    // Region R2 (67 MB): y1hl interleaved (enc1 out) -> Zt interleaved
    float* r2 = (float*)d_ws + ACT;
    unsigned short* y1hl = (unsigned short*)r2;
    unsigned short* Zt   = (unsigned short*)r2;
    // small region
    float* sm    = r2 + R2F;
    int*   idxI  = (int*)sm;                            // [BT]
    float* cn    = (float*)(idxI + BT);                 // [NCODE]
    float* cbt   = cn + NCODE;                          // [Dc*NCODE]
    float* wt1   = cbt + (size_t)Dc * NCODE;            // enc_w1t: 80*3*512
    float* wt3   = wt1 + (size_t)INC * 3 * Hc;          // dec_w1t: 512*3*512
    float* candv = wt3 + (size_t)Dc * 3 * Hc;           // [8*BT]
    float* cand2v= candv + (size_t)8 * BT;              // [8*BT]
    int*   candi = (int*)(cand2v + (size_t)8 * BT);     // [8*BT]
    int*   flagn = candi + (size_t)8 * BT;              // [4]
    int*   flaglist = flagn + 4;                        // [BT]
    float* G     = (float*)(flaglist + BT);             // [NCODE*1536]
    unsigned short* whl  = (unsigned short*)(G + (size_t)NCODE * 1536); // [3*Hc*1024]
    unsigned short* cbhl = whl + (size_t)3 * Hc * 1024;                 // [NCODE*1024]
    unsigned short* wh2  = cbhl + (size_t)NCODE * 1024;                 // [3*INC*Hc]
    float* melsT = (float*)(wh2 + (size_t)3 * INC * Hc);                // [B,80,T]

    dim3 blk(256);
    hipMemsetAsync(flagn, 0, 16, stream);
    // prep: norms + transposes + bf16 splits
    code_norms<<<dim3(NCODE), dim3(64), 0, stream>>>(codebook, cn);
    cb_transpose<<<dim3(NCODE / 64, Dc / 64), blk, 0, stream>>>(codebook, cbt);
    mels_transpose<<<dim3(Tn / 64, Bsz), blk, 0, stream>>>(mels, melsT);
    wt_transpose<<<dim3(Hc / 64, INC / 16), blk, 0, stream>>>(enc_w1, wt1, INC, Hc);
    wsplit<<<dim3(Hc, 3), blk, 0, stream>>>(enc_w2, whl);
    cbsplit<<<dim3(NCODE), blk, 0, stream>>>(codebook, cbhl);
    wt_transpose<<<dim3(Hc / 64, Dc / 16), blk, 0, stream>>>(dec_w1, wt3, Dc, Hc);
    wsplit80<<<dim3(INC, 3), blk, 0, stream>>>(dec_w2, wh2);
    // decoder conv1 folded matrix (independent of activations)
    gemm_g<<<dim3(NCODE / 64, 12), blk, 0, stream>>>(cbt, wt3, G);
    // encoder (enc1 writes interleaved y1hl directly)
    zero_guards<<<dim3(Bsz), blk, 0, stream>>>(y1hl);
    conv_enc1<<<dim3(Tn / 64, Hc / 128, Bsz), blk, 0, stream>>>(melsT, wt1, enc_b1,
                                                                y1hl);
    conv_mid_mfma<<<dim3(Tn / 64, Hc / 128, Bsz), blk, 0, stream>>>(y1hl, whl,
                                                                    enc_b2, zf);
    // z -> interleaved hi/lo for vq staging (y1hl dead now; serial reuse of R2)
    split_t<<<dim3(Tn / 64, Hc / 64, Bsz), blk, 0, stream>>>(zf, Zt, Tn, 0);
    // vector quantization: MFMA approx + margin-guarded exact rescue (fp32 z)
    vq_mfma<<<dim3(BT / 64, NCODE / 128), blk, 0, stream>>>(Zt, cbhl, cn,
                                                            candv, candi, cand2v);
    vq_reduce2<<<dim3(BT / 256), blk, 0, stream>>>(candv, candi, cand2v, idxI,
                                                   idxf, flagn, flaglist);
    vq_rescue<<<dim3(128), blk, 0, stream>>>(flagn, flaglist, zf, codebook, cn,
                                             idxI, idxf);
    // decoder: conv1 via gather of G rows, then conv2 as single-bf16 MFMA
    dec_y3<<<dim3(Tn / 64, 4, Bsz), blk, 0, stream>>>(idxI, G, dec_b1, y3);
    dec2_mfma<<<dim3(Tn / 128, 1, Bsz), blk, 0, stream>>>(y3, wh2, dec_b2, recon);
}

// Round 5
// 793.734 us; speedup vs baseline: 1.3378x; 1.3378x over previous
//
#include <hip/hip_runtime.h>
#include <hip/hip_bf16.h>

// Problem constants
#define Bsz   16
#define Tn    2048
#define INC   80
#define Hc    512
#define Dc    512
#define NCODE 1024
#define BT    (Bsz * Tn)           // 32768
#define RECON_N (Bsz * Tn * INC)   // 2,621,440
#define MARGIN 0.03f               // approx-distance safety margin

typedef __attribute__((ext_vector_type(8))) short bf16x8;
typedef __attribute__((ext_vector_type(4))) float f32x4;
typedef __attribute__((ext_vector_type(4))) unsigned short u16x4;

// float -> bf16 (round-to-nearest-even), and back
static __device__ __forceinline__ unsigned short f2bf(float x) {
    unsigned u = __float_as_uint(x);
    u += 0x7FFF + ((u >> 16) & 1);
    return (unsigned short)(u >> 16);
}
static __device__ __forceinline__ float bf2f(unsigned short h) {
    return __uint_as_float((unsigned)h << 16);
}

// async global->LDS 16B copy (global_load_lds_dwordx4).
typedef const __attribute__((address_space(1))) unsigned int* gas_p;
typedef __attribute__((address_space(3))) unsigned int* las_p;
static __device__ __forceinline__ void async16(const void* g, const void* l) {
    __builtin_amdgcn_global_load_lds(
        (gas_p)(unsigned long long)g,
        (las_p)(unsigned int)(unsigned long long)l,
        16, 0, 0);
}

// ---------------------------------------------------------------------------
// code_norms: CN[j] = sum_d CB[j][d]^2
// ---------------------------------------------------------------------------
__global__ __launch_bounds__(64)
void code_norms(const float* __restrict__ CB, float* __restrict__ CN) {
    int j = blockIdx.x;
    int lane = threadIdx.x;
    const float4* row = (const float4*)(CB + (size_t)j * Dc);
    float s = 0.f;
    #pragma unroll
    for (int i = 0; i < 2; ++i) {
        float4 v = row[lane + i * 64];
        s = fmaf(v.x, v.x, s);
        s = fmaf(v.y, v.y, s);
        s = fmaf(v.z, v.z, s);
        s = fmaf(v.w, v.w, s);
    }
    #pragma unroll
    for (int off = 32; off > 0; off >>= 1) s += __shfl_down(s, off, 64);
    if (lane == 0) CN[j] = s;
}

// ---------------------------------------------------------------------------
// cb_transpose: CBt[d][j] = CB[j][d].  grid (NCODE/64, Dc/64), block 256
// ---------------------------------------------------------------------------
__global__ __launch_bounds__(256)
void cb_transpose(const float* __restrict__ CB, float* __restrict__ CBt) {
    const int j0 = blockIdx.x * 64;
    const int d0 = blockIdx.y * 64;
    __shared__ float ts[64][65];
    const int tid = threadIdx.x;
    for (int i = tid; i < 4096; i += 256) {
        int r = i >> 6, c = i & 63;
        ts[r][c] = CB[(size_t)(j0 + r) * Dc + d0 + c];
    }
    __syncthreads();
    for (int i = tid; i < 4096; i += 256) {
        int r = i >> 6, c = i & 63;
        CBt[(size_t)(d0 + r) * NCODE + j0 + c] = ts[c][r];
    }
}

// ---------------------------------------------------------------------------
// mels_transpose: MT[b][c][t] = M[b][t][c].  grid (Tn/64, Bsz), block 256
// ---------------------------------------------------------------------------
__global__ __launch_bounds__(256)
void mels_transpose(const float* __restrict__ M, float* __restrict__ MT) {
    const int t0 = blockIdx.x * 64;
    const int b  = blockIdx.y;
    __shared__ float ts[64][84];
    const int tid = threadIdx.x;
    #pragma unroll
    for (int it = 0; it < 5; ++it) {
        int i = tid + it * 256;            // < 1280
        int t = i / 20, c4 = i % 20;
        *(float4*)&ts[t][c4 * 4] =
            *(const float4*)&M[((size_t)b * Tn + t0 + t) * INC + c4 * 4];
    }
    __syncthreads();
    #pragma unroll
    for (int it = 0; it < 20; ++it) {
        int i = tid + it * 256;            // < 5120
        int c = i >> 6, t = i & 63;
        MT[((size_t)b * INC + c) * Tn + t0 + t] = ts[t][c];
    }
}

// ---------------------------------------------------------------------------
// wt_transpose: Wt[(c*3+k)*Cout + o] = W[(o*Cin + c)*3 + k]
// ---------------------------------------------------------------------------
__global__ __launch_bounds__(256)
void wt_transpose(const float* __restrict__ W, float* __restrict__ Wt,
                  int Cin, int Cout) {
    const int o0 = blockIdx.x * 64;
    const int c0 = blockIdx.y * 16;
    __shared__ float ts[48][65];
    const int tid = threadIdx.x;
    for (int i = tid; i < 64 * 48; i += 256) {
        int o = i / 48, ck = i % 48;
        int oo = o0 + o;
        float v = 0.f;
        if (oo < Cout) v = W[(size_t)oo * Cin * 3 + c0 * 3 + ck];
        ts[ck][o] = v;
    }
    __syncthreads();
    for (int i = tid; i < 48 * 64; i += 256) {
        int o = i & 63, ck = i >> 6;
        int oo = o0 + o;
        if (oo < Cout) Wt[(size_t)(c0 * 3 + ck) * Cout + oo] = ts[ck][o];
    }
}

// ---------------------------------------------------------------------------
// wsplit: enc_w2 [o][c][k] fp32 -> Whl interleaved bf16
// [k][o][16 groups][hi32|lo32] so a lane's Ah/Al pair shares one cache line.
// ---------------------------------------------------------------------------
__global__ __launch_bounds__(256)
void wsplit(const float* __restrict__ W, unsigned short* __restrict__ Whl) {
    int o = blockIdx.x, k = blockIdx.y;
    #pragma unroll
    for (int it = 0; it < 2; ++it) {
        int c = threadIdx.x + it * 256;
        float v = W[((size_t)o * Hc + c) * 3 + k];
        unsigned short h = f2bf(v);
        size_t base = ((size_t)(k * Hc + o) * 16 + (c >> 5)) * 64 + (c & 31);
        Whl[base] = h;
        Whl[base + 32] = f2bf(v - bf2f(h));
    }
}

// ---------------------------------------------------------------------------
// wsplit80: dec_w2 [o][c][k] fp32 -> Wh2 [k][o][c] bf16 (hi only).
// ---------------------------------------------------------------------------
__global__ __launch_bounds__(256)
void wsplit80(const float* __restrict__ W, unsigned short* __restrict__ Wh) {
    int o = blockIdx.x, k = blockIdx.y;
    #pragma unroll
    for (int it = 0; it < 2; ++it) {
        int c = threadIdx.x + it * 256;
        Wh[((size_t)k * INC + o) * Hc + c] = f2bf(W[((size_t)o * Hc + c) * 3 + k]);
    }
}

// ---------------------------------------------------------------------------
// cbsplit: codebook [j][d] fp32 -> CBhl interleaved [j][16][hi32|lo32].
// ---------------------------------------------------------------------------
__global__ __launch_bounds__(256)
void cbsplit(const float* __restrict__ CB, unsigned short* __restrict__ CBhl) {
    int j = blockIdx.x;
    #pragma unroll
    for (int it = 0; it < 2; ++it) {
        int d = threadIdx.x + it * 256;
        float v = CB[(size_t)j * Dc + d];
        unsigned short h = f2bf(v);
        size_t base = ((size_t)j * 16 + (d >> 5)) * 64 + (d & 31);
        CBhl[base] = h;
        CBhl[base + 32] = f2bf(v - bf2f(h));
    }
}

// ---------------------------------------------------------------------------
// conv_enc1: melsT [B,80,T] -> y1hl interleaved bf16 hi/lo, K=3, ReLU.
// ---------------------------------------------------------------------------
__global__ __launch_bounds__(256)
void conv_enc1(const float* __restrict__ X, const float* __restrict__ Wt,
               const float* __restrict__ bias, unsigned short* __restrict__ Yhl) {
    const int t0 = blockIdx.x * 64;
    const int o0 = blockIdx.y * 128;
    const int b  = blockIdx.z;
    union SharedU {
        struct { float Xs[16][72]; float Ws[48][132]; } a;
        float Ys[128][69];
    };
    __shared__ __align__(16) SharedU su;
    float (&Xs)[16][72]  = su.a.Xs;
    float (&Ws)[48][132] = su.a.Ws;
    const int tid = threadIdx.x;
    const int tx = tid & 15, ty = tid >> 4;
    float acc[8][4] = {};
    const float* Xb = X + (size_t)b * INC * Tn;

    for (int c0 = 0; c0 < INC; c0 += 16) {
        for (int i = tid; i < 16 * 66; i += 256) {
            int cc = i / 66, tt = i % 66;
            int t = t0 + tt - 1;
            float v = 0.f;
            if (t >= 0 && t < Tn) v = Xb[(size_t)(c0 + cc) * Tn + t];
            Xs[cc][tt] = v;
        }
        for (int i = tid; i < 48 * 128; i += 256) {
            int o = i & 127, ck = i >> 7;
            Ws[ck][o] = Wt[(size_t)(c0 * 3 + ck) * Hc + o0 + o];
        }
        __syncthreads();
        #pragma unroll
        for (int cc = 0; cc < 16; ++cc) {
            float4 xa = *(const float4*)&Xs[cc][tx * 4];
            float2 xb2 = *(const float2*)&Xs[cc][tx * 4 + 4];
            float xv[6] = {xa.x, xa.y, xa.z, xa.w, xb2.x, xb2.y};
            #pragma unroll
            for (int k = 0; k < 3; ++k) {
                float4 wa = *(const float4*)&Ws[cc * 3 + k][ty * 4];
                float4 wb = *(const float4*)&Ws[cc * 3 + k][64 + ty * 4];
                float wv[8] = {wa.x, wa.y, wa.z, wa.w, wb.x, wb.y, wb.z, wb.w};
                #pragma unroll
                for (int i8 = 0; i8 < 8; ++i8)
                    #pragma unroll
                    for (int j = 0; j < 4; ++j)
                        acc[i8][j] = fmaf(wv[i8], xv[k + j], acc[i8][j]);
            }
        }
        __syncthreads();
    }
    #pragma unroll
    for (int og = 0; og < 2; ++og)
        #pragma unroll
        for (int oi = 0; oi < 4; ++oi) {
            int ol = og * 64 + ty * 4 + oi;
            float bv = bias[o0 + ol];
            const int i8 = og * 4 + oi;
            #pragma unroll
            for (int j = 0; j < 4; ++j)
                su.Ys[ol][tx * 4 + j] = fmaxf(acc[i8][j] + bv, 0.f);
        }
    __syncthreads();
    #pragma unroll
    for (int it = 0; it < 8; ++it) {
        int i = tid + it * 256;            // 2048 = 32 o-quads x 64 t
        int oq = i & 31, t = i >> 5;
        int o4 = o0 + oq * 4;
        u16x4 h, l;
        #pragma unroll
        for (int r = 0; r < 4; ++r) {
            float v = su.Ys[oq * 4 + r][t];
            unsigned short hh = f2bf(v);
            h[r] = hh;
            l[r] = f2bf(v - bf2f(hh));
        }
        size_t base = ((size_t)(b * (Tn + 2) + 1 + t0 + t) * 16 + (o4 >> 5)) * 64
                      + (o4 & 31);
        *(u16x4*)(Yhl + base) = h;
        *(u16x4*)(Yhl + base + 32) = l;
    }
}

// ---------------------------------------------------------------------------
// zero_guards: zero padded guard rows (t=-1 and t=Tn), 1024-ushort rows.
// ---------------------------------------------------------------------------
__global__ __launch_bounds__(256)
void zero_guards(unsigned short* __restrict__ Yhl) {
    const int b = blockIdx.x;
    u16x4 z = {0, 0, 0, 0};
    size_t r0 = (size_t)(b * (Tn + 2)) * 1024;
    size_t r1 = (size_t)(b * (Tn + 2) + Tn + 1) * 1024;
    *(u16x4*)(Yhl + r0 + threadIdx.x * 4) = z;
    *(u16x4*)(Yhl + r1 + threadIdx.x * 4) = z;
}

// ---------------------------------------------------------------------------
// zero_guards512: guard rows for the 512-ushort-row y3t buffer.
// ---------------------------------------------------------------------------
__global__ __launch_bounds__(256)
void zero_guards512(unsigned short* __restrict__ Y) {
    const int b = blockIdx.x;
    u16x4 z = {0, 0, 0, 0};
    size_t r0 = (size_t)(b * (Tn + 2)) * 512;
    size_t r1 = (size_t)(b * (Tn + 2) + Tn + 1) * 512;
    if (threadIdx.x < 128) {
        *(u16x4*)(Y + r0 + threadIdx.x * 4) = z;
        *(u16x4*)(Y + r1 + threadIdx.x * 4) = z;
    }
}

// ---------------------------------------------------------------------------
// split_t: X fp32 [B][512][Tn] -> Yhl interleaved bf16 (z -> Zt).
// grid (Tn/64, 512/64, B), block 256.
// ---------------------------------------------------------------------------
__global__ __launch_bounds__(256)
void split_t(const float* __restrict__ X, unsigned short* __restrict__ Yhl,
             int rowStride, int rowOff) {
    const int t0 = blockIdx.x * 64;
    const int c0 = blockIdx.y * 64;
    const int b  = blockIdx.z;
    __shared__ __align__(16) float ts[64][68];
    const int tid = threadIdx.x;
    #pragma unroll
    for (int it = 0; it < 4; ++it) {
        int i = tid + it * 256;            // < 1024
        int cc = i >> 4, t4 = i & 15;
        float4 v = *(const float4*)&X[((size_t)b * Hc + c0 + cc) * Tn + t0 + t4 * 4];
        ts[t4 * 4 + 0][cc] = v.x;
        ts[t4 * 4 + 1][cc] = v.y;
        ts[t4 * 4 + 2][cc] = v.z;
        ts[t4 * 4 + 3][cc] = v.w;
    }
    __syncthreads();
    #pragma unroll
    for (int it = 0; it < 4; ++it) {
        int i = tid + it * 256;            // < 1024
        int t = i >> 4, c4 = i & 15;
        int c = c0 + c4 * 4;
        float4 v = *(const float4*)&ts[t][c4 * 4];
        float va[4] = {v.x, v.y, v.z, v.w};
        u16x4 h, l;
        #pragma unroll
        for (int r = 0; r < 4; ++r) {
            unsigned short hh = f2bf(va[r]);
            h[r] = hh;
            l[r] = f2bf(va[r] - bf2f(hh));
        }
        size_t base = ((size_t)(b * rowStride + rowOff + t0 + t) * 16 + (c >> 5)) * 64
                      + (c & 31);
        *(u16x4*)(Yhl + base) = h;
        *(u16x4*)(Yhl + base + 32) = l;
    }
}

// ---------------------------------------------------------------------------
// conv_mid_mfma: implicit GEMM, async16 staging, XOR-swizzled LDS, merged
// hi/lo weight lines, setprio, XCD-aware block swizzle (each XCD owns 2
// batches -> 3MB weight set stays L2-resident; o-blocks of a t-tile adjacent).
// grid (Tn/128, Hc/128, B) = 1024 blocks, block 256. Writes exact fp32 z.
// ---------------------------------------------------------------------------
__global__ __launch_bounds__(256)
void conv_mid_mfma(const unsigned short* __restrict__ Xhl,
                   const unsigned short* __restrict__ Whl,
                   const float* __restrict__ bias,
                   float* __restrict__ Y) {
    // XCD swizzle: lin%8 = XCD. XCD x -> b in {2x, 2x+1}; within: t-major, o inner.
    const int lin  = blockIdx.x + (blockIdx.y << 4) + (blockIdx.z << 6);
    const int slot = lin >> 3;                   // 0..127
    const int b  = ((lin & 7) << 1) | (slot >> 6);
    const int t0 = ((slot & 63) >> 2) << 7;      // t-block 0..15
    const int o0 = (slot & 3) << 7;              // o-block 0..3
    __shared__ __align__(16) unsigned short XL[2][136 * 64];  // 2 x 17408 B
    const int tid  = threadIdx.x;
    const int lane = tid & 63;
    const int wave = tid >> 6;
    const int wm = wave >> 1, wn = wave & 1;
    const int m16 = lane & 15;
    const int q = lane >> 4;
    const int lrow = lane >> 3;
    const int lchk = (lane & 7) ^ lrow;
    const unsigned short* Xb = Xhl + ((size_t)b * (Tn + 2) + t0) * 1024
                               + (size_t)lrow * 1024 + lchk * 8;

    f32x4 acc[4][4];
    #pragma unroll
    for (int mt = 0; mt < 4; ++mt)
        #pragma unroll
        for (int nt = 0; nt < 4; ++nt)
            acc[mt][nt] = (f32x4){0.f, 0.f, 0.f, 0.f};

    #pragma unroll
    for (int i = 0; i < 5; ++i) {
        int ii = wave + i * 4;
        if (ii < 17)
            async16(Xb + (size_t)ii * 8192, &XL[0][ii * 512]);
    }

    for (int c0 = 0; c0 < Hc; c0 += 32) {
        const int buf = (c0 >> 5) & 1;
        __syncthreads();   // drains vmcnt(0): buf is ready, buf^1 free
        if (c0 + 32 < Hc) {
            const unsigned short* src = Xb + (size_t)((c0 >> 5) + 1) * 64;
            #pragma unroll
            for (int i = 0; i < 5; ++i) {
                int ii = wave + i * 4;
                if (ii < 17)
                    async16(src + (size_t)ii * 8192, &XL[buf ^ 1][ii * 512]);
            }
        }
        #pragma unroll
        for (int k = 0; k < 3; ++k) {
            bf16x8 Ah[4], Al[4];
            #pragma unroll
            for (int mt = 0; mt < 4; ++mt) {
                int o = o0 + wm * 64 + mt * 16 + m16;
                size_t base = ((size_t)(k * Hc + o) * 16 + (c0 >> 5)) * 64 + q * 8;
                Ah[mt] = *(const bf16x8*)(Whl + base);
                Al[mt] = *(const bf16x8*)(Whl + base + 32);
            }
            #pragma unroll
            for (int nt = 0; nt < 4; ++nt) {
                int row = wn * 64 + nt * 16 + m16 + k;   // 0..129
                const unsigned short* rp = &XL[buf][row * 64];
                int ph = (q ^ (row & 7)) * 8;            // hi phys chunk
                union { bf16x8 v; uint4 u; } bh, bl;
                bh.u = *(const uint4*)(rp + ph);
                bl.u = *(const uint4*)(rp + (ph ^ 32));  // lo = hi slot ^ 4
                __builtin_amdgcn_s_setprio(1);
                #pragma unroll
                for (int mt = 0; mt < 4; ++mt)
                    acc[mt][nt] = __builtin_amdgcn_mfma_f32_16x16x32_bf16(
                        Ah[mt], bh.v, acc[mt][nt], 0, 0, 0);
                #pragma unroll
                for (int mt = 0; mt < 4; ++mt)
                    acc[mt][nt] = __builtin_amdgcn_mfma_f32_16x16x32_bf16(
                        Al[mt], bh.v, acc[mt][nt], 0, 0, 0);
                #pragma unroll
                for (int mt = 0; mt < 4; ++mt)
                    acc[mt][nt] = __builtin_amdgcn_mfma_f32_16x16x32_bf16(
                        Ah[mt], bl.v, acc[mt][nt], 0, 0, 0);
                __builtin_amdgcn_s_setprio(0);
            }
        }
    }
    float* Yb = Y + (size_t)b * Hc * Tn;
    #pragma unroll
    for (int mt = 0; mt < 4; ++mt) {
        int ob = o0 + wm * 64 + mt * 16 + q * 4;
        float4 bq = *(const float4*)&bias[ob];
        float bqa[4] = {bq.x, bq.y, bq.z, bq.w};
        #pragma unroll
        for (int nt = 0; nt < 4; ++nt) {
            int t = t0 + wn * 64 + nt * 16 + m16;
            #pragma unroll
            for (int r = 0; r < 4; ++r)
                Yb[(size_t)(ob + r) * Tn + t] = acc[mt][nt][r] + bqa[r];
        }
    }
}

// ---------------------------------------------------------------------------
// dec2_mfma: recon = conv(y3t bf16, dec_w2) + b. Clone of conv_mid staging:
// async16 + XOR-swizzle, 64-c groups (single bf16), double-buffered.
// grid (Tn/128, 1, B), block 256.
// ---------------------------------------------------------------------------
__global__ __launch_bounds__(256)
void dec2_mfma(const unsigned short* __restrict__ Xt,
               const unsigned short* __restrict__ Wh2,
               const float* __restrict__ bias, float* __restrict__ OUT) {
    const int t0 = blockIdx.x * 128;
    const int b  = blockIdx.z;
    __shared__ __align__(16) unsigned short XL[2][136 * 64];  // 2 x 17408 B
    const int tid = threadIdx.x;
    const int lane = tid & 63;
    const int wave = tid >> 6;
    const int wn = wave;               // wave = t-quadrant (32 t each)
    const int m16 = lane & 15;
    const int q = lane >> 4;
    const int lrow = lane >> 3;
    const int lchk = (lane & 7) ^ lrow;
    // rows stride 512 ushorts; group slice = 64 ushorts (64 c, single bf16)
    const unsigned short* Xb = Xt + ((size_t)b * (Tn + 2) + t0) * 512
                               + (size_t)lrow * 512 + lchk * 8;

    f32x4 acc[5][2];
    #pragma unroll
    for (int mt = 0; mt < 5; ++mt)
        #pragma unroll
        for (int nt = 0; nt < 2; ++nt)
            acc[mt][nt] = (f32x4){0.f, 0.f, 0.f, 0.f};

    // prologue: stage group 0 (17 instrs x 8 rows x 128B)
    #pragma unroll
    for (int i = 0; i < 5; ++i) {
        int ii = wave + i * 4;
        if (ii < 17)
            async16(Xb + (size_t)ii * 4096, &XL[0][ii * 512]);
    }

    for (int c0 = 0; c0 < Hc; c0 += 64) {
        const int buf = (c0 >> 6) & 1;
        __syncthreads();
        if (c0 + 64 < Hc) {
            const unsigned short* src = Xb + (size_t)((c0 >> 6) + 1) * 64;
            #pragma unroll
            for (int i = 0; i < 5; ++i) {
                int ii = wave + i * 4;
                if (ii < 17)
                    async16(src + (size_t)ii * 4096, &XL[buf ^ 1][ii * 512]);
            }
        }
        #pragma unroll
        for (int k = 0; k < 3; ++k) {
            #pragma unroll
            for (int sub = 0; sub < 2; ++sub) {
                int c = c0 + sub * 32;
                bf16x8 Ah[5];
                #pragma unroll
                for (int mt = 0; mt < 5; ++mt) {
                    int o = mt * 16 + m16;
                    Ah[mt] = *(const bf16x8*)(Wh2 + ((size_t)(k * INC + o)) * Hc
                                              + c + q * 8);
                }
                #pragma unroll
                for (int nt = 0; nt < 2; ++nt) {
                    int row = wn * 32 + nt * 16 + m16 + k;   // 0..129
                    const unsigned short* rp = &XL[buf][row * 64];
                    int p = sub * 4 + q;
                    int ph = (p ^ (row & 7)) * 8;
                    union { bf16x8 v; uint4 u; } bh;
                    bh.u = *(const uint4*)(rp + ph);
                    #pragma unroll
                    for (int mt = 0; mt < 5; ++mt)
                        acc[mt][nt] = __builtin_amdgcn_mfma_f32_16x16x32_bf16(
                            Ah[mt], bh.v, acc[mt][nt], 0, 0, 0);
                }
            }
        }
    }
    #pragma unroll
    for (int mt = 0; mt < 5; ++mt) {
        float4 bq = *(const float4*)&bias[mt * 16 + q * 4];
        #pragma unroll
        for (int nt = 0; nt < 2; ++nt) {
            int t = t0 + wn * 32 + nt * 16 + m16;
            float4 r;
            r.x = acc[mt][nt][0] + bq.x;
            r.y = acc[mt][nt][1] + bq.y;
            r.z = acc[mt][nt][2] + bq.z;
            r.w = acc[mt][nt][3] + bq.w;
            *(float4*)(OUT + ((size_t)b * Tn + t) * INC + mt * 16 + q * 4) = r;
        }
    }
}

// ---------------------------------------------------------------------------
// vq_mfma: approx distances via 3xbf16 MFMA GEMM reading pre-split Zt;
// async16 staging, merged CBhl lines, setprio, XCD swizzle (2 batches/XCD).
// grid (BT/128, NCODE/128) = 2048 blocks, block 256.
// ---------------------------------------------------------------------------
__global__ __launch_bounds__(256)
void vq_mfma(const unsigned short* __restrict__ Zt,
             const unsigned short* __restrict__ CBhl,
             const float* __restrict__ CN,
             float* __restrict__ candv, int* __restrict__ candi,
             float* __restrict__ cand2v) {
    // XCD swizzle: lin%8 = XCD; XCD x -> nb in [32x, 32x+32) (2 batches), all jb.
    const int lin  = blockIdx.x + (blockIdx.y << 8);
    const int slotB = lin >> 3;                  // 0..255
    const int nb = ((lin & 7) << 5) | (slotB & 31);
    const int jb = slotB >> 5;                   // 0..7
    const int b  = nb >> 4;
    const int t0 = (nb & 15) * 128;
    const int jbase = jb * 128;
    __shared__ __align__(16) unsigned char pool[32768];
    unsigned short* XL0 = (unsigned short*)pool;            // 16384 B
    unsigned short* XL1 = (unsigned short*)(pool + 16384);  // 16384 B
    float* RV = (float*)pool;                                // reused after
    int*   RI = (int*)(pool + 4096);
    float* R2 = (float*)(pool + 8192);

    const int tid = threadIdx.x;
    const int lane = tid & 63;
    const int wave = tid >> 6;
    const int wm = wave >> 1, wn = wave & 1;
    const int m16 = lane & 15;
    const int q = lane >> 4;
    const int lrow = lane >> 3;
    const int lchk = (lane & 7) ^ lrow;
    const unsigned short* Zb = Zt + (size_t)(b * Tn + t0) * 1024
                               + (size_t)lrow * 1024 + lchk * 8;

    f32x4 acc[4][4];
    #pragma unroll
    for (int mt = 0; mt < 4; ++mt)
        #pragma unroll
        for (int nt = 0; nt < 4; ++nt)
            acc[mt][nt] = (f32x4){0.f, 0.f, 0.f, 0.f};

    #pragma unroll
    for (int i = 0; i < 4; ++i) {
        int ii = wave + i * 4;
        async16(Zb + (size_t)ii * 8192, XL0 + ii * 512);
    }

    for (int d0 = 0; d0 < Dc; d0 += 32) {
        const int buf = (d0 >> 5) & 1;
        unsigned short* XL = buf ? XL1 : XL0;
        __syncthreads();
        if (d0 + 32 < Dc) {
            unsigned short* XN = buf ? XL0 : XL1;
            const unsigned short* src = Zb + (size_t)((d0 >> 5) + 1) * 64;
            #pragma unroll
            for (int i = 0; i < 4; ++i) {
                int ii = wave + i * 4;
                async16(src + (size_t)ii * 8192, XN + ii * 512);
            }
        }
        bf16x8 Ah[4], Al[4];
        #pragma unroll
        for (int mt = 0; mt < 4; ++mt) {
            int j = jbase + wm * 64 + mt * 16 + m16;
            size_t base = ((size_t)j * 16 + (d0 >> 5)) * 64 + q * 8;
            Ah[mt] = *(const bf16x8*)(CBhl + base);
            Al[mt] = *(const bf16x8*)(CBhl + base + 32);
        }
        #pragma unroll
        for (int nt = 0; nt < 4; ++nt) {
            int row = wn * 64 + nt * 16 + m16;
            const unsigned short* rp = XL + row * 64;
            int ph = (q ^ (row & 7)) * 8;
            union { bf16x8 v; uint4 u; } bh, bl;
            bh.u = *(const uint4*)(rp + ph);
            bl.u = *(const uint4*)(rp + (ph ^ 32));
            __builtin_amdgcn_s_setprio(1);
            #pragma unroll
            for (int mt = 0; mt < 4; ++mt)
                acc[mt][nt] = __builtin_amdgcn_mfma_f32_16x16x32_bf16(
                    Ah[mt], bh.v, acc[mt][nt], 0, 0, 0);
            #pragma unroll
            for (int mt = 0; mt < 4; ++mt)
                acc[mt][nt] = __builtin_amdgcn_mfma_f32_16x16x32_bf16(
                    Al[mt], bh.v, acc[mt][nt], 0, 0, 0);
            #pragma unroll
            for (int mt = 0; mt < 4; ++mt)
                acc[mt][nt] = __builtin_amdgcn_mfma_f32_16x16x32_bf16(
                    Ah[mt], bl.v, acc[mt][nt], 0, 0, 0);
            __builtin_amdgcn_s_setprio(0);
        }
    }
    __syncthreads();

    float cn4[4][4];
    #pragma unroll
    for (int mt = 0; mt < 4; ++mt) {
        float4 c = *(const float4*)&CN[jbase + wm * 64 + mt * 16 + q * 4];
        cn4[mt][0] = c.x; cn4[mt][1] = c.y; cn4[mt][2] = c.z; cn4[mt][3] = c.w;
    }
    #pragma unroll
    for (int nt = 0; nt < 4; ++nt) {
        int t = wn * 64 + nt * 16 + m16;
        float v1 = 1e30f, v2 = 1e30f;
        int i1 = 0;
        #pragma unroll
        for (int mt = 0; mt < 4; ++mt)
            #pragma unroll
            for (int r = 0; r < 4; ++r) {
                float d = fmaf(-2.f, acc[mt][nt][r], cn4[mt][r]);
                int j = jbase + wm * 64 + mt * 16 + q * 4 + r;
                if (d < v1 || (d == v1 && j < i1)) { v2 = v1; v1 = d; i1 = j; }
                else if (d < v2) v2 = d;
            }
        int slotw = wm * 4 + q;
        RV[t * 8 + slotw] = v1;
        RI[t * 8 + slotw] = i1;
        R2[t * 8 + slotw] = v2;
    }
    __syncthreads();
    if (tid < 128) {
        int t = tid;
        float v1 = RV[t * 8], v2 = R2[t * 8];
        int i1 = RI[t * 8];
        #pragma unroll
        for (int s = 1; s < 8; ++s) {
            float a1 = RV[t * 8 + s], a2 = R2[t * 8 + s];
            int ai = RI[t * 8 + s];
            if (a1 < v1 || (a1 == v1 && ai < i1)) {
                v2 = fminf(v1, a2); v1 = a1; i1 = ai;
            } else {
                v2 = fminf(v2, a1);
            }
        }
        int n = b * Tn + t0 + t;
        candv[(size_t)jb * BT + n] = v1;
        candi[(size_t)jb * BT + n] = i1;
        cand2v[(size_t)jb * BT + n] = v2;
    }
}

// ---------------------------------------------------------------------------
// vq_reduce2: merge 8 j-block candidates; flag near-ties for exact rescore.
// ---------------------------------------------------------------------------
__global__ __launch_bounds__(256)
void vq_reduce2(const float* __restrict__ candv, const int* __restrict__ candi,
                const float* __restrict__ cand2v, int* __restrict__ idxI,
                float* __restrict__ idxf, int* __restrict__ flagn,
                int* __restrict__ flaglist) {
    int n = blockIdx.x * 256 + threadIdx.x;
    float v1 = candv[n], v2 = cand2v[n];
    int i1 = candi[n];
    #pragma unroll
    for (int jq = 1; jq < 8; ++jq) {
        float a1 = candv[(size_t)jq * BT + n];
        float a2 = cand2v[(size_t)jq * BT + n];
        int ai = candi[(size_t)jq * BT + n];
        if (a1 < v1 || (a1 == v1 && ai < i1)) {
            v2 = fminf(v1, a2); v1 = a1; i1 = ai;
        } else {
            v2 = fminf(v2, a1);
        }
    }
    idxI[n] = i1;
    idxf[n] = (float)i1;
    if (v2 - v1 < MARGIN) {
        int s = atomicAdd(flagn, 1);
        flaglist[s] = n;
    }
}

// ---------------------------------------------------------------------------
// vq_rescue: exact fp32 re-score of flagged positions over all 1024 codes.
// ---------------------------------------------------------------------------
__global__ __launch_bounds__(256)
void vq_rescue(const int* __restrict__ flagn, const int* __restrict__ flaglist,
               const float* __restrict__ Z, const float* __restrict__ CB,
               const float* __restrict__ CN, int* __restrict__ idxI,
               float* __restrict__ idxf) {
    __shared__ float zs[512];
    __shared__ float rvv[256];
    __shared__ int   rii[256];
    const int nf = *flagn;
    for (int f = blockIdx.x; f < nf; f += gridDim.x) {
        int n = flaglist[f];
        int b = n / Tn, t = n - b * Tn;
        __syncthreads();
        #pragma unroll
        for (int it = 0; it < 2; ++it) {
            int d = threadIdx.x + it * 256;
            zs[d] = Z[((size_t)b * Dc + d) * Tn + t];
        }
        __syncthreads();
        float bv = 1e30f;
        int bi = 0;
        #pragma unroll
        for (int jj = 0; jj < 4; ++jj) {
            int j = threadIdx.x * 4 + jj;
            const float* cr = CB + (size_t)j * Dc;
            float dot = 0.f;
            for (int d = 0; d < Dc; ++d) dot = fmaf(zs[d], cr[d], dot);
            float dist = fmaf(-2.f, dot, CN[j]);
            if (dist < bv || (dist == bv && j < bi)) { bv = dist; bi = j; }
        }
        rvv[threadIdx.x] = bv;
        rii[threadIdx.x] = bi;
        __syncthreads();
        for (int off = 128; off > 0; off >>= 1) {
            if (threadIdx.x < off) {
                float ov = rvv[threadIdx.x + off];
                int oi = rii[threadIdx.x + off];
                if (ov < rvv[threadIdx.x] ||
                    (ov == rvv[threadIdx.x] && oi < rii[threadIdx.x])) {
                    rvv[threadIdx.x] = ov; rii[threadIdx.x] = oi;
                }
            }
            __syncthreads();
        }
        if (threadIdx.x == 0) {
            idxI[n] = rii[0];
            idxf[n] = (float)rii[0];
        }
    }
}

// ---------------------------------------------------------------------------
// gemm_g: G[j][kk*512+o] = sum_c CB[j][c] * dec_w1[o][c][kk].
// ---------------------------------------------------------------------------
__global__ __launch_bounds__(256)
void gemm_g(const float* __restrict__ CBt, const float* __restrict__ Wt,
            float* __restrict__ G) {
    const int j0 = blockIdx.x * 64;
    const int kk = blockIdx.y >> 2;
    const int o0 = (blockIdx.y & 3) * 128;
    __shared__ __align__(16) float As[16][68];
    __shared__ __align__(16) float Bs[16][132];
    const int tid = threadIdx.x;
    const int tx = tid & 15, ty = tid >> 4;
    float acc[4][8] = {};

    for (int c0 = 0; c0 < Dc; c0 += 16) {
        {
            int cc = tid >> 4, j4 = tid & 15;
            *(float4*)&As[cc][j4 * 4] =
                *(const float4*)&CBt[(size_t)(c0 + cc) * NCODE + j0 + j4 * 4];
        }
        #pragma unroll
        for (int it = 0; it < 2; ++it) {
            int i = tid + it * 256;
            int cc = i >> 5, o4 = i & 31;
            *(float4*)&Bs[cc][o4 * 4] =
                *(const float4*)&Wt[(size_t)((c0 + cc) * 3 + kk) * Hc + o0 + o4 * 4];
        }
        __syncthreads();
        #pragma unroll
        for (int cc = 0; cc < 16; ++cc) {
            float4 a = *(const float4*)&As[cc][tx * 4];
            float av[4] = {a.x, a.y, a.z, a.w};
            float4 b0 = *(const float4*)&Bs[cc][ty * 4];
            float4 b1 = *(const float4*)&Bs[cc][64 + ty * 4];
            float bv[8] = {b0.x, b0.y, b0.z, b0.w, b1.x, b1.y, b1.z, b1.w};
            #pragma unroll
            for (int jj = 0; jj < 4; ++jj)
                #pragma unroll
                for (int oo = 0; oo < 8; ++oo)
                    acc[jj][oo] = fmaf(av[jj], bv[oo], acc[jj][oo]);
        }
        __syncthreads();
    }
    #pragma unroll
    for (int jj = 0; jj < 4; ++jj) {
        int j = j0 + tx * 4 + jj;
        float* gp = G + (size_t)j * 1536 + kk * 512 + o0;
        *(float4*)(gp + ty * 4) = *(float4*)&acc[jj][0];
        *(float4*)(gp + 64 + ty * 4) = *(float4*)&acc[jj][4];
    }
}

// ---------------------------------------------------------------------------
// dec_y3: y3t[b][t][o] (bf16, rows of 512, +guards) =
//   f2bf(relu(b1[o] + sum_kk G[idx[b][t+kk-1]][kk*512+o])).
// Bit-identical to previous fp32-write + f2bf-in-dec2 path.
// ---------------------------------------------------------------------------
__global__ __launch_bounds__(256)
void dec_y3(const int* __restrict__ idx, const float* __restrict__ G,
            const float* __restrict__ bias, unsigned short* __restrict__ Yt) {
    const int t0 = blockIdx.x * 64;
    const int o0 = blockIdx.y * 128;
    const int b  = blockIdx.z;
    const int tid = threadIdx.x;
    __shared__ int sidx[66];
    __shared__ __align__(16) float Ys[128][68];

    if (tid < 66) {
        int t = t0 + tid - 1;
        sidx[tid] = (t >= 0 && t < Tn) ? idx[b * Tn + t] : -1;
    }
    __syncthreads();

    const int o = tid & 127;
    const int half = tid >> 7;
    float acc[32] = {};
    #pragma unroll
    for (int kk = 0; kk < 3; ++kk) {
        const float* Gk = G + (size_t)kk * 512 + o0 + o;
        #pragma unroll
        for (int k = 0; k < 32; ++k) {
            int j = sidx[half + 2 * k + kk];
            if (j >= 0) acc[k] += Gk[(size_t)j * 1536];
        }
    }
    float bv = bias[o0 + o];
    #pragma unroll
    for (int k = 0; k < 32; ++k)
        Ys[o][half + 2 * k] = fmaxf(acc[k] + bv, 0.f);
    __syncthreads();

    unsigned short* Yb = Yt + ((size_t)(b * (Tn + 2) + 1 + t0)) * 512 + o0;
    #pragma unroll
    for (int it = 0; it < 8; ++it) {
        int i = tid + it * 256;            // 2048 = 32 o-quads x 64 t
        int t = i >> 5, oq = i & 31;
        u16x4 h;
        #pragma unroll
        for (int r = 0; r < 4; ++r)
            h[r] = f2bf(Ys[oq * 4 + r][t]);
        *(u16x4*)(Yb + (size_t)t * 512 + oq * 4) = h;
    }
}

// ---------------------------------------------------------------------------
extern "C" void kernel_launch(void* const* d_in, const int* in_sizes, int n_in,
                              void* d_out, int out_size, void* d_ws, size_t ws_size,
                              hipStream_t stream) {
    const float* mels    = (const float*)d_in[0];
    const float* enc_w1  = (const float*)d_in[1];
    const float* enc_b1  = (const float*)d_in[2];
    const float* enc_w2  = (const float*)d_in[3];
    const float* enc_b2  = (const float*)d_in[4];
    const float* codebook= (const float*)d_in[5];
    const float* dec_w1  = (const float*)d_in[6];
    const float* dec_b1  = (const float*)d_in[7];
    const float* dec_w2  = (const float*)d_in[8];
    const float* dec_b2  = (const float*)d_in[9];

    float* out = (float*)d_out;
    float* recon = out;                 // [B,T,80]
    float* idxf  = out + RECON_N;       // [B,T] as float

    const size_t ACT = (size_t)Bsz * Hc * Tn;          // 16,777,216 floats
    const size_t Y1HL_U = (size_t)Bsz * (Tn + 2) * 1024 + 16384; // ushorts+slack
    const size_t R2F = Y1HL_U / 2;                      // floats

    // Region R1 (64 MB): z fp32 (conv_mid out, rescue reads) -> later y3t bf16
    float* zf = (float*)d_ws;
    unsigned short* y3t = (unsigned short*)d_ws;
    // Region R2 (67 MB): y1hl interleaved (enc1 out) -> Zt interleaved
    float* r2 = (float*)d_ws + ACT;
    unsigned short* y1hl = (unsigned short*)r2;
    unsigned short* Zt   = (unsigned short*)r2;
    // small region
    float* sm    = r2 + R2F;
    int*   idxI  = (int*)sm;                            // [BT]
    float* cn    = (float*)(idxI + BT);                 // [NCODE]
    float* cbt   = cn + NCODE;                          // [Dc*NCODE]
    float* wt1   = cbt + (size_t)Dc * NCODE;            // enc_w1t: 80*3*512
    float* wt3   = wt1 + (size_t)INC * 3 * Hc;          // dec_w1t: 512*3*512
    float* candv = wt3 + (size_t)Dc * 3 * Hc;           // [8*BT]
    float* cand2v= candv + (size_t)8 * BT;              // [8*BT]
    int*   candi = (int*)(cand2v + (size_t)8 * BT);     // [8*BT]
    int*   flagn = candi + (size_t)8 * BT;              // [4]
    int*   flaglist = flagn + 4;                        // [BT]
    float* G     = (float*)(flaglist + BT);             // [NCODE*1536]
    unsigned short* whl  = (unsigned short*)(G + (size_t)NCODE * 1536); // [3*Hc*1024]
    unsigned short* cbhl = whl + (size_t)3 * Hc * 1024;                 // [NCODE*1024]
    unsigned short* wh2  = cbhl + (size_t)NCODE * 1024;                 // [3*INC*Hc]
    float* melsT = (float*)(wh2 + (size_t)3 * INC * Hc);                // [B,80,T]

    dim3 blk(256);
    hipMemsetAsync(flagn, 0, 16, stream);
    // prep: norms + transposes + bf16 splits
    code_norms<<<dim3(NCODE), dim3(64), 0, stream>>>(codebook, cn);
    cb_transpose<<<dim3(NCODE / 64, Dc / 64), blk, 0, stream>>>(codebook, cbt);
    mels_transpose<<<dim3(Tn / 64, Bsz), blk, 0, stream>>>(mels, melsT);
    wt_transpose<<<dim3(Hc / 64, INC / 16), blk, 0, stream>>>(enc_w1, wt1, INC, Hc);
    wsplit<<<dim3(Hc, 3), blk, 0, stream>>>(enc_w2, whl);
    cbsplit<<<dim3(NCODE), blk, 0, stream>>>(codebook, cbhl);
    wt_transpose<<<dim3(Hc / 64, Dc / 16), blk, 0, stream>>>(dec_w1, wt3, Dc, Hc);
    wsplit80<<<dim3(INC, 3), blk, 0, stream>>>(dec_w2, wh2);
    // decoder conv1 folded matrix (independent of activations)
    gemm_g<<<dim3(NCODE / 64, 12), blk, 0, stream>>>(cbt, wt3, G);
    // encoder (enc1 writes interleaved y1hl directly)
    zero_guards<<<dim3(Bsz), blk, 0, stream>>>(y1hl);
    conv_enc1<<<dim3(Tn / 64, Hc / 128, Bsz), blk, 0, stream>>>(melsT, wt1, enc_b1,
                                                                y1hl);
    conv_mid_mfma<<<dim3(Tn / 128, Hc / 128, Bsz), blk, 0, stream>>>(y1hl, whl,
                                                                     enc_b2, zf);
    // z -> interleaved hi/lo for vq staging (y1hl dead now; serial reuse of R2)
    split_t<<<dim3(Tn / 64, Hc / 64, Bsz), blk, 0, stream>>>(zf, Zt, Tn, 0);
    // vector quantization: MFMA approx + margin-guarded exact rescue (fp32 z)
    vq_mfma<<<dim3(BT / 128, NCODE / 128), blk, 0, stream>>>(Zt, cbhl, cn,
                                                             candv, candi, cand2v);
    vq_reduce2<<<dim3(BT / 256), blk, 0, stream>>>(candv, candi, cand2v, idxI,
                                                   idxf, flagn, flaglist);
    vq_rescue<<<dim3(128), blk, 0, stream>>>(flagn, flaglist, zf, codebook, cn,
                                             idxI, idxf);
    // decoder: conv1 via gather of G rows (bf16 out), conv2 via async16 MFMA
    zero_guards512<<<dim3(Bsz), blk, 0, stream>>>(y3t);   // after rescue (aliases zf)
    dec_y3<<<dim3(Tn / 64, 4, Bsz), blk, 0, stream>>>(idxI, G, dec_b1, y3t);
    dec2_mfma<<<dim3(Tn / 128, 1, Bsz), blk, 0, stream>>>(y3t, wh2, dec_b2, recon);
}

// Round 6
// 790.613 us; speedup vs baseline: 1.3431x; 1.0039x over previous
//
#include <hip/hip_runtime.h>
#include <hip/hip_bf16.h>

// Problem constants
#define Bsz   16
#define Tn    2048
#define INC   80
#define Hc    512
#define Dc    512
#define NCODE 1024
#define BT    (Bsz * Tn)           // 32768
#define RECON_N (Bsz * Tn * INC)   // 2,621,440
#define MARGIN 0.03f               // approx-distance safety margin

typedef __attribute__((ext_vector_type(8))) short bf16x8;
typedef __attribute__((ext_vector_type(4))) float f32x4;
typedef __attribute__((ext_vector_type(4))) unsigned short u16x4;

// float -> bf16 (round-to-nearest-even), and back
static __device__ __forceinline__ unsigned short f2bf(float x) {
    unsigned u = __float_as_uint(x);
    u += 0x7FFF + ((u >> 16) & 1);
    return (unsigned short)(u >> 16);
}
static __device__ __forceinline__ float bf2f(unsigned short h) {
    return __uint_as_float((unsigned)h << 16);
}

// async global->LDS 16B copy (global_load_lds_dwordx4).
typedef const __attribute__((address_space(1))) unsigned int* gas_p;
typedef __attribute__((address_space(3))) unsigned int* las_p;
static __device__ __forceinline__ void async16(const void* g, const void* l) {
    __builtin_amdgcn_global_load_lds(
        (gas_p)(unsigned long long)g,
        (las_p)(unsigned int)(unsigned long long)l,
        16, 0, 0);
}

// ---------------------------------------------------------------------------
// code_norms: CN[j] = sum_d CB[j][d]^2
// ---------------------------------------------------------------------------
__global__ __launch_bounds__(64)
void code_norms(const float* __restrict__ CB, float* __restrict__ CN) {
    int j = blockIdx.x;
    int lane = threadIdx.x;
    const float4* row = (const float4*)(CB + (size_t)j * Dc);
    float s = 0.f;
    #pragma unroll
    for (int i = 0; i < 2; ++i) {
        float4 v = row[lane + i * 64];
        s = fmaf(v.x, v.x, s);
        s = fmaf(v.y, v.y, s);
        s = fmaf(v.z, v.z, s);
        s = fmaf(v.w, v.w, s);
    }
    #pragma unroll
    for (int off = 32; off > 0; off >>= 1) s += __shfl_down(s, off, 64);
    if (lane == 0) CN[j] = s;
}

// ---------------------------------------------------------------------------
// cb_transpose: CBt[d][j] = CB[j][d].  grid (NCODE/64, Dc/64), block 256
// ---------------------------------------------------------------------------
__global__ __launch_bounds__(256)
void cb_transpose(const float* __restrict__ CB, float* __restrict__ CBt) {
    const int j0 = blockIdx.x * 64;
    const int d0 = blockIdx.y * 64;
    __shared__ float ts[64][65];
    const int tid = threadIdx.x;
    for (int i = tid; i < 4096; i += 256) {
        int r = i >> 6, c = i & 63;
        ts[r][c] = CB[(size_t)(j0 + r) * Dc + d0 + c];
    }
    __syncthreads();
    for (int i = tid; i < 4096; i += 256) {
        int r = i >> 6, c = i & 63;
        CBt[(size_t)(d0 + r) * NCODE + j0 + c] = ts[c][r];
    }
}

// ---------------------------------------------------------------------------
// mels_transpose: MT[b][c][t] = M[b][t][c].  grid (Tn/64, Bsz), block 256
// ---------------------------------------------------------------------------
__global__ __launch_bounds__(256)
void mels_transpose(const float* __restrict__ M, float* __restrict__ MT) {
    const int t0 = blockIdx.x * 64;
    const int b  = blockIdx.y;
    __shared__ float ts[64][84];
    const int tid = threadIdx.x;
    #pragma unroll
    for (int it = 0; it < 5; ++it) {
        int i = tid + it * 256;            // < 1280
        int t = i / 20, c4 = i % 20;
        *(float4*)&ts[t][c4 * 4] =
            *(const float4*)&M[((size_t)b * Tn + t0 + t) * INC + c4 * 4];
    }
    __syncthreads();
    #pragma unroll
    for (int it = 0; it < 20; ++it) {
        int i = tid + it * 256;            // < 5120
        int c = i >> 6, t = i & 63;
        MT[((size_t)b * INC + c) * Tn + t0 + t] = ts[t][c];
    }
}

// ---------------------------------------------------------------------------
// wt_transpose: Wt[(c*3+k)*Cout + o] = W[(o*Cin + c)*3 + k]
// ---------------------------------------------------------------------------
__global__ __launch_bounds__(256)
void wt_transpose(const float* __restrict__ W, float* __restrict__ Wt,
                  int Cin, int Cout) {
    const int o0 = blockIdx.x * 64;
    const int c0 = blockIdx.y * 16;
    __shared__ float ts[48][65];
    const int tid = threadIdx.x;
    for (int i = tid; i < 64 * 48; i += 256) {
        int o = i / 48, ck = i % 48;
        int oo = o0 + o;
        float v = 0.f;
        if (oo < Cout) v = W[(size_t)oo * Cin * 3 + c0 * 3 + ck];
        ts[ck][o] = v;
    }
    __syncthreads();
    for (int i = tid; i < 48 * 64; i += 256) {
        int o = i & 63, ck = i >> 6;
        int oo = o0 + o;
        if (oo < Cout) Wt[(size_t)(c0 * 3 + ck) * Cout + oo] = ts[ck][o];
    }
}

// ---------------------------------------------------------------------------
// wsplit: enc_w2 [o][c][k] fp32 -> Whl interleaved bf16
// [k][o][16 groups][hi32|lo32] so a lane's Ah/Al pair shares one cache line.
// ---------------------------------------------------------------------------
__global__ __launch_bounds__(256)
void wsplit(const float* __restrict__ W, unsigned short* __restrict__ Whl) {
    int o = blockIdx.x, k = blockIdx.y;
    #pragma unroll
    for (int it = 0; it < 2; ++it) {
        int c = threadIdx.x + it * 256;
        float v = W[((size_t)o * Hc + c) * 3 + k];
        unsigned short h = f2bf(v);
        size_t base = ((size_t)(k * Hc + o) * 16 + (c >> 5)) * 64 + (c & 31);
        Whl[base] = h;
        Whl[base + 32] = f2bf(v - bf2f(h));
    }
}

// ---------------------------------------------------------------------------
// wsplit80: dec_w2 [o][c][k] fp32 -> Wh2 [k][o][c] bf16 (hi only).
// ---------------------------------------------------------------------------
__global__ __launch_bounds__(256)
void wsplit80(const float* __restrict__ W, unsigned short* __restrict__ Wh) {
    int o = blockIdx.x, k = blockIdx.y;
    #pragma unroll
    for (int it = 0; it < 2; ++it) {
        int c = threadIdx.x + it * 256;
        Wh[((size_t)k * INC + o) * Hc + c] = f2bf(W[((size_t)o * Hc + c) * 3 + k]);
    }
}

// ---------------------------------------------------------------------------
// cbsplit: codebook [j][d] fp32 -> CBhl interleaved [j][16][hi32|lo32].
// ---------------------------------------------------------------------------
__global__ __launch_bounds__(256)
void cbsplit(const float* __restrict__ CB, unsigned short* __restrict__ CBhl) {
    int j = blockIdx.x;
    #pragma unroll
    for (int it = 0; it < 2; ++it) {
        int d = threadIdx.x + it * 256;
        float v = CB[(size_t)j * Dc + d];
        unsigned short h = f2bf(v);
        size_t base = ((size_t)j * 16 + (d >> 5)) * 64 + (d & 31);
        CBhl[base] = h;
        CBhl[base + 32] = f2bf(v - bf2f(h));
    }
}

// ---------------------------------------------------------------------------
// conv_enc1: melsT [B,80,T] -> y1hl interleaved bf16 hi/lo, K=3, ReLU.
// Guard-row zeroing folded in (blocks at t-extremes zero their o-slice).
// ---------------------------------------------------------------------------
__global__ __launch_bounds__(256)
void conv_enc1(const float* __restrict__ X, const float* __restrict__ Wt,
               const float* __restrict__ bias, unsigned short* __restrict__ Yhl) {
    const int t0 = blockIdx.x * 64;
    const int o0 = blockIdx.y * 128;
    const int b  = blockIdx.z;
    union SharedU {
        struct { float Xs[16][72]; float Ws[48][132]; } a;
        float Ys[128][69];
    };
    __shared__ __align__(16) SharedU su;
    float (&Xs)[16][72]  = su.a.Xs;
    float (&Ws)[48][132] = su.a.Ws;
    const int tid = threadIdx.x;
    const int tx = tid & 15, ty = tid >> 4;
    float acc[8][4] = {};
    const float* Xb = X + (size_t)b * INC * Tn;

    // guard rows (t=-1 and t=Tn): zero this block's 4 o-groups (256 ushorts)
    if (blockIdx.x == 0 && tid < 64) {
        u16x4 z4 = {0, 0, 0, 0};
        *(u16x4*)(Yhl + ((size_t)(b * (Tn + 2)) * 16 + (o0 >> 5)) * 64 + tid * 4) = z4;
    }
    if (blockIdx.x == Tn / 64 - 1 && tid < 64) {
        u16x4 z4 = {0, 0, 0, 0};
        *(u16x4*)(Yhl + ((size_t)(b * (Tn + 2) + Tn + 1) * 16 + (o0 >> 5)) * 64
                  + tid * 4) = z4;
    }

    for (int c0 = 0; c0 < INC; c0 += 16) {
        for (int i = tid; i < 16 * 66; i += 256) {
            int cc = i / 66, tt = i % 66;
            int t = t0 + tt - 1;
            float v = 0.f;
            if (t >= 0 && t < Tn) v = Xb[(size_t)(c0 + cc) * Tn + t];
            Xs[cc][tt] = v;
        }
        for (int i = tid; i < 48 * 128; i += 256) {
            int o = i & 127, ck = i >> 7;
            Ws[ck][o] = Wt[(size_t)(c0 * 3 + ck) * Hc + o0 + o];
        }
        __syncthreads();
        #pragma unroll
        for (int cc = 0; cc < 16; ++cc) {
            float4 xa = *(const float4*)&Xs[cc][tx * 4];
            float2 xb2 = *(const float2*)&Xs[cc][tx * 4 + 4];
            float xv[6] = {xa.x, xa.y, xa.z, xa.w, xb2.x, xb2.y};
            #pragma unroll
            for (int k = 0; k < 3; ++k) {
                float4 wa = *(const float4*)&Ws[cc * 3 + k][ty * 4];
                float4 wb = *(const float4*)&Ws[cc * 3 + k][64 + ty * 4];
                float wv[8] = {wa.x, wa.y, wa.z, wa.w, wb.x, wb.y, wb.z, wb.w};
                #pragma unroll
                for (int i8 = 0; i8 < 8; ++i8)
                    #pragma unroll
                    for (int j = 0; j < 4; ++j)
                        acc[i8][j] = fmaf(wv[i8], xv[k + j], acc[i8][j]);
            }
        }
        __syncthreads();
    }
    #pragma unroll
    for (int og = 0; og < 2; ++og)
        #pragma unroll
        for (int oi = 0; oi < 4; ++oi) {
            int ol = og * 64 + ty * 4 + oi;
            float bv = bias[o0 + ol];
            const int i8 = og * 4 + oi;
            #pragma unroll
            for (int j = 0; j < 4; ++j)
                su.Ys[ol][tx * 4 + j] = fmaxf(acc[i8][j] + bv, 0.f);
        }
    __syncthreads();
    #pragma unroll
    for (int it = 0; it < 8; ++it) {
        int i = tid + it * 256;            // 2048 = 32 o-quads x 64 t
        int oq = i & 31, t = i >> 5;
        int o4 = o0 + oq * 4;
        u16x4 h, l;
        #pragma unroll
        for (int r = 0; r < 4; ++r) {
            float v = su.Ys[oq * 4 + r][t];
            unsigned short hh = f2bf(v);
            h[r] = hh;
            l[r] = f2bf(v - bf2f(hh));
        }
        size_t base = ((size_t)(b * (Tn + 2) + 1 + t0 + t) * 16 + (o4 >> 5)) * 64
                      + (o4 & 31);
        *(u16x4*)(Yhl + base) = h;
        *(u16x4*)(Yhl + base + 32) = l;
    }
}

// ---------------------------------------------------------------------------
// conv_mid_mfma: implicit GEMM, async16 staging, XOR-swizzled LDS, merged
// hi/lo weight lines, setprio, XCD swizzle. Epilogue writes z directly as
// interleaved Zt (hi|lo, bit-identical to the old split_t output) plus a
// lo2 residual plane so vq_rescue can reconstruct z to 2^-27 relative
// (500x below the error scale that flipped idx in round 1). fp32 z dropped.
// grid (Tn/128, Hc/128, B) = 1024 blocks, block 256.
// ---------------------------------------------------------------------------
__global__ __launch_bounds__(256)
void conv_mid_mfma(const unsigned short* __restrict__ Xhl,
                   const unsigned short* __restrict__ Whl,
                   const float* __restrict__ bias,
                   unsigned short* __restrict__ Zt,
                   unsigned short* __restrict__ Lo2) {
    // XCD swizzle: lin%8 = XCD. XCD x -> b in {2x, 2x+1}; within: t-major, o inner.
    const int lin  = blockIdx.x + (blockIdx.y << 4) + (blockIdx.z << 6);
    const int slot = lin >> 3;                   // 0..127
    const int b  = ((lin & 7) << 1) | (slot >> 6);
    const int t0 = ((slot & 63) >> 2) << 7;      // t-block 0..15
    const int o0 = (slot & 3) << 7;              // o-block 0..3
    __shared__ __align__(16) unsigned short XL[2][136 * 64];  // 2 x 17408 B
    const int tid  = threadIdx.x;
    const int lane = tid & 63;
    const int wave = tid >> 6;
    const int wm = wave >> 1, wn = wave & 1;
    const int m16 = lane & 15;
    const int q = lane >> 4;
    const int lrow = lane >> 3;
    const int lchk = (lane & 7) ^ lrow;
    const unsigned short* Xb = Xhl + ((size_t)b * (Tn + 2) + t0) * 1024
                               + (size_t)lrow * 1024 + lchk * 8;

    f32x4 acc[4][4];
    #pragma unroll
    for (int mt = 0; mt < 4; ++mt)
        #pragma unroll
        for (int nt = 0; nt < 4; ++nt)
            acc[mt][nt] = (f32x4){0.f, 0.f, 0.f, 0.f};

    #pragma unroll
    for (int i = 0; i < 5; ++i) {
        int ii = wave + i * 4;
        if (ii < 17)
            async16(Xb + (size_t)ii * 8192, &XL[0][ii * 512]);
    }

    for (int c0 = 0; c0 < Hc; c0 += 32) {
        const int buf = (c0 >> 5) & 1;
        __syncthreads();   // drains vmcnt(0): buf is ready, buf^1 free
        if (c0 + 32 < Hc) {
            const unsigned short* src = Xb + (size_t)((c0 >> 5) + 1) * 64;
            #pragma unroll
            for (int i = 0; i < 5; ++i) {
                int ii = wave + i * 4;
                if (ii < 17)
                    async16(src + (size_t)ii * 8192, &XL[buf ^ 1][ii * 512]);
            }
        }
        #pragma unroll
        for (int k = 0; k < 3; ++k) {
            bf16x8 Ah[4], Al[4];
            #pragma unroll
            for (int mt = 0; mt < 4; ++mt) {
                int o = o0 + wm * 64 + mt * 16 + m16;
                size_t base = ((size_t)(k * Hc + o) * 16 + (c0 >> 5)) * 64 + q * 8;
                Ah[mt] = *(const bf16x8*)(Whl + base);
                Al[mt] = *(const bf16x8*)(Whl + base + 32);
            }
            #pragma unroll
            for (int nt = 0; nt < 4; ++nt) {
                int row = wn * 64 + nt * 16 + m16 + k;   // 0..129
                const unsigned short* rp = &XL[buf][row * 64];
                int ph = (q ^ (row & 7)) * 8;            // hi phys chunk
                union { bf16x8 v; uint4 u; } bh, bl;
                bh.u = *(const uint4*)(rp + ph);
                bl.u = *(const uint4*)(rp + (ph ^ 32));  // lo = hi slot ^ 4
                __builtin_amdgcn_s_setprio(1);
                #pragma unroll
                for (int mt = 0; mt < 4; ++mt)
                    acc[mt][nt] = __builtin_amdgcn_mfma_f32_16x16x32_bf16(
                        Ah[mt], bh.v, acc[mt][nt], 0, 0, 0);
                #pragma unroll
                for (int mt = 0; mt < 4; ++mt)
                    acc[mt][nt] = __builtin_amdgcn_mfma_f32_16x16x32_bf16(
                        Al[mt], bh.v, acc[mt][nt], 0, 0, 0);
                #pragma unroll
                for (int mt = 0; mt < 4; ++mt)
                    acc[mt][nt] = __builtin_amdgcn_mfma_f32_16x16x32_bf16(
                        Ah[mt], bl.v, acc[mt][nt], 0, 0, 0);
                __builtin_amdgcn_s_setprio(0);
            }
        }
    }
    // epilogue: bias + triple-split write (Zt hi/lo interleaved + lo2 plane)
    unsigned short* Lb = Lo2 + (size_t)b * Tn * 512;
    #pragma unroll
    for (int mt = 0; mt < 4; ++mt) {
        int ob = o0 + wm * 64 + mt * 16 + q * 4;
        float4 bq = *(const float4*)&bias[ob];
        float bqa[4] = {bq.x, bq.y, bq.z, bq.w};
        #pragma unroll
        for (int nt = 0; nt < 4; ++nt) {
            int t = t0 + wn * 64 + nt * 16 + m16;
            u16x4 h, l, l2;
            #pragma unroll
            for (int r = 0; r < 4; ++r) {
                float v = acc[mt][nt][r] + bqa[r];
                unsigned short hh = f2bf(v);
                float r1 = v - bf2f(hh);
                unsigned short ll = f2bf(r1);
                h[r] = hh;
                l[r] = ll;
                l2[r] = f2bf(r1 - bf2f(ll));
            }
            size_t zb = ((size_t)(b * Tn + t) * 16 + (ob >> 5)) * 64 + (ob & 31);
            *(u16x4*)(Zt + zb) = h;
            *(u16x4*)(Zt + zb + 32) = l;
            *(u16x4*)(Lb + (size_t)t * 512 + ob) = l2;
        }
    }
}

// ---------------------------------------------------------------------------
// dec2_mfma: recon = conv(y3t bf16, dec_w2) + b. async16 + XOR-swizzle,
// 64-c groups (single bf16), double-buffered. grid (Tn/128, 1, B), block 256.
// ---------------------------------------------------------------------------
__global__ __launch_bounds__(256)
void dec2_mfma(const unsigned short* __restrict__ Xt,
               const unsigned short* __restrict__ Wh2,
               const float* __restrict__ bias, float* __restrict__ OUT) {
    const int t0 = blockIdx.x * 128;
    const int b  = blockIdx.z;
    __shared__ __align__(16) unsigned short XL[2][136 * 64];  // 2 x 17408 B
    const int tid = threadIdx.x;
    const int lane = tid & 63;
    const int wave = tid >> 6;
    const int wn = wave;               // wave = t-quadrant (32 t each)
    const int m16 = lane & 15;
    const int q = lane >> 4;
    const int lrow = lane >> 3;
    const int lchk = (lane & 7) ^ lrow;
    const unsigned short* Xb = Xt + ((size_t)b * (Tn + 2) + t0) * 512
                               + (size_t)lrow * 512 + lchk * 8;

    f32x4 acc[5][2];
    #pragma unroll
    for (int mt = 0; mt < 5; ++mt)
        #pragma unroll
        for (int nt = 0; nt < 2; ++nt)
            acc[mt][nt] = (f32x4){0.f, 0.f, 0.f, 0.f};

    #pragma unroll
    for (int i = 0; i < 5; ++i) {
        int ii = wave + i * 4;
        if (ii < 17)
            async16(Xb + (size_t)ii * 4096, &XL[0][ii * 512]);
    }

    for (int c0 = 0; c0 < Hc; c0 += 64) {
        const int buf = (c0 >> 6) & 1;
        __syncthreads();
        if (c0 + 64 < Hc) {
            const unsigned short* src = Xb + (size_t)((c0 >> 6) + 1) * 64;
            #pragma unroll
            for (int i = 0; i < 5; ++i) {
                int ii = wave + i * 4;
                if (ii < 17)
                    async16(src + (size_t)ii * 4096, &XL[buf ^ 1][ii * 512]);
            }
        }
        #pragma unroll
        for (int k = 0; k < 3; ++k) {
            #pragma unroll
            for (int sub = 0; sub < 2; ++sub) {
                int c = c0 + sub * 32;
                bf16x8 Ah[5];
                #pragma unroll
                for (int mt = 0; mt < 5; ++mt) {
                    int o = mt * 16 + m16;
                    Ah[mt] = *(const bf16x8*)(Wh2 + ((size_t)(k * INC + o)) * Hc
                                              + c + q * 8);
                }
                #pragma unroll
                for (int nt = 0; nt < 2; ++nt) {
                    int row = wn * 32 + nt * 16 + m16 + k;   // 0..129
                    const unsigned short* rp = &XL[buf][row * 64];
                    int p = sub * 4 + q;
                    int ph = (p ^ (row & 7)) * 8;
                    union { bf16x8 v; uint4 u; } bh;
                    bh.u = *(const uint4*)(rp + ph);
                    #pragma unroll
                    for (int mt = 0; mt < 5; ++mt)
                        acc[mt][nt] = __builtin_amdgcn_mfma_f32_16x16x32_bf16(
                            Ah[mt], bh.v, acc[mt][nt], 0, 0, 0);
                }
            }
        }
    }
    #pragma unroll
    for (int mt = 0; mt < 5; ++mt) {
        float4 bq = *(const float4*)&bias[mt * 16 + q * 4];
        #pragma unroll
        for (int nt = 0; nt < 2; ++nt) {
            int t = t0 + wn * 32 + nt * 16 + m16;
            float4 r;
            r.x = acc[mt][nt][0] + bq.x;
            r.y = acc[mt][nt][1] + bq.y;
            r.z = acc[mt][nt][2] + bq.z;
            r.w = acc[mt][nt][3] + bq.w;
            *(float4*)(OUT + ((size_t)b * Tn + t) * INC + mt * 16 + q * 4) = r;
        }
    }
}

// ---------------------------------------------------------------------------
// vq_mfma: approx distances via 3xbf16 MFMA GEMM reading Zt (now written by
// conv_mid directly); async16 staging, merged CBhl lines, setprio, XCD swizzle.
// grid (BT/128, NCODE/128) = 2048 blocks, block 256.
// ---------------------------------------------------------------------------
__global__ __launch_bounds__(256)
void vq_mfma(const unsigned short* __restrict__ Zt,
             const unsigned short* __restrict__ CBhl,
             const float* __restrict__ CN,
             float* __restrict__ candv, int* __restrict__ candi,
             float* __restrict__ cand2v) {
    // XCD swizzle: lin%8 = XCD; XCD x -> nb in [32x, 32x+32) (2 batches), all jb.
    const int lin  = blockIdx.x + (blockIdx.y << 8);
    const int slotB = lin >> 3;                  // 0..255
    const int nb = ((lin & 7) << 5) | (slotB & 31);
    const int jb = slotB >> 5;                   // 0..7
    const int b  = nb >> 4;
    const int t0 = (nb & 15) * 128;
    const int jbase = jb * 128;
    __shared__ __align__(16) unsigned char pool[32768];
    unsigned short* XL0 = (unsigned short*)pool;            // 16384 B
    unsigned short* XL1 = (unsigned short*)(pool + 16384);  // 16384 B
    float* RV = (float*)pool;                                // reused after
    int*   RI = (int*)(pool + 4096);
    float* R2 = (float*)(pool + 8192);

    const int tid = threadIdx.x;
    const int lane = tid & 63;
    const int wave = tid >> 6;
    const int wm = wave >> 1, wn = wave & 1;
    const int m16 = lane & 15;
    const int q = lane >> 4;
    const int lrow = lane >> 3;
    const int lchk = (lane & 7) ^ lrow;
    const unsigned short* Zb = Zt + (size_t)(b * Tn + t0) * 1024
                               + (size_t)lrow * 1024 + lchk * 8;

    f32x4 acc[4][4];
    #pragma unroll
    for (int mt = 0; mt < 4; ++mt)
        #pragma unroll
        for (int nt = 0; nt < 4; ++nt)
            acc[mt][nt] = (f32x4){0.f, 0.f, 0.f, 0.f};

    #pragma unroll
    for (int i = 0; i < 4; ++i) {
        int ii = wave + i * 4;
        async16(Zb + (size_t)ii * 8192, XL0 + ii * 512);
    }

    for (int d0 = 0; d0 < Dc; d0 += 32) {
        const int buf = (d0 >> 5) & 1;
        unsigned short* XL = buf ? XL1 : XL0;
        __syncthreads();
        if (d0 + 32 < Dc) {
            unsigned short* XN = buf ? XL0 : XL1;
            const unsigned short* src = Zb + (size_t)((d0 >> 5) + 1) * 64;
            #pragma unroll
            for (int i = 0; i < 4; ++i) {
                int ii = wave + i * 4;
                async16(src + (size_t)ii * 8192, XN + ii * 512);
            }
        }
        bf16x8 Ah[4], Al[4];
        #pragma unroll
        for (int mt = 0; mt < 4; ++mt) {
            int j = jbase + wm * 64 + mt * 16 + m16;
            size_t base = ((size_t)j * 16 + (d0 >> 5)) * 64 + q * 8;
            Ah[mt] = *(const bf16x8*)(CBhl + base);
            Al[mt] = *(const bf16x8*)(CBhl + base + 32);
        }
        #pragma unroll
        for (int nt = 0; nt < 4; ++nt) {
            int row = wn * 64 + nt * 16 + m16;
            const unsigned short* rp = XL + row * 64;
            int ph = (q ^ (row & 7)) * 8;
            union { bf16x8 v; uint4 u; } bh, bl;
            bh.u = *(const uint4*)(rp + ph);
            bl.u = *(const uint4*)(rp + (ph ^ 32));
            __builtin_amdgcn_s_setprio(1);
            #pragma unroll
            for (int mt = 0; mt < 4; ++mt)
                acc[mt][nt] = __builtin_amdgcn_mfma_f32_16x16x32_bf16(
                    Ah[mt], bh.v, acc[mt][nt], 0, 0, 0);
            #pragma unroll
            for (int mt = 0; mt < 4; ++mt)
                acc[mt][nt] = __builtin_amdgcn_mfma_f32_16x16x32_bf16(
                    Al[mt], bh.v, acc[mt][nt], 0, 0, 0);
            #pragma unroll
            for (int mt = 0; mt < 4; ++mt)
                acc[mt][nt] = __builtin_amdgcn_mfma_f32_16x16x32_bf16(
                    Ah[mt], bl.v, acc[mt][nt], 0, 0, 0);
            __builtin_amdgcn_s_setprio(0);
        }
    }
    __syncthreads();

    float cn4[4][4];
    #pragma unroll
    for (int mt = 0; mt < 4; ++mt) {
        float4 c = *(const float4*)&CN[jbase + wm * 64 + mt * 16 + q * 4];
        cn4[mt][0] = c.x; cn4[mt][1] = c.y; cn4[mt][2] = c.z; cn4[mt][3] = c.w;
    }
    #pragma unroll
    for (int nt = 0; nt < 4; ++nt) {
        int t = wn * 64 + nt * 16 + m16;
        float v1 = 1e30f, v2 = 1e30f;
        int i1 = 0;
        #pragma unroll
        for (int mt = 0; mt < 4; ++mt)
            #pragma unroll
            for (int r = 0; r < 4; ++r) {
                float d = fmaf(-2.f, acc[mt][nt][r], cn4[mt][r]);
                int j = jbase + wm * 64 + mt * 16 + q * 4 + r;
                if (d < v1 || (d == v1 && j < i1)) { v2 = v1; v1 = d; i1 = j; }
                else if (d < v2) v2 = d;
            }
        int slotw = wm * 4 + q;
        RV[t * 8 + slotw] = v1;
        RI[t * 8 + slotw] = i1;
        R2[t * 8 + slotw] = v2;
    }
    __syncthreads();
    if (tid < 128) {
        int t = tid;
        float v1 = RV[t * 8], v2 = R2[t * 8];
        int i1 = RI[t * 8];
        #pragma unroll
        for (int s = 1; s < 8; ++s) {
            float a1 = RV[t * 8 + s], a2 = R2[t * 8 + s];
            int ai = RI[t * 8 + s];
            if (a1 < v1 || (a1 == v1 && ai < i1)) {
                v2 = fminf(v1, a2); v1 = a1; i1 = ai;
            } else {
                v2 = fminf(v2, a1);
            }
        }
        int n = b * Tn + t0 + t;
        candv[(size_t)jb * BT + n] = v1;
        candi[(size_t)jb * BT + n] = i1;
        cand2v[(size_t)jb * BT + n] = v2;
    }
}

// ---------------------------------------------------------------------------
// vq_reduce2: merge 8 j-block candidates; flag near-ties for exact rescore.
// ---------------------------------------------------------------------------
__global__ __launch_bounds__(256)
void vq_reduce2(const float* __restrict__ candv, const int* __restrict__ candi,
                const float* __restrict__ cand2v, int* __restrict__ idxI,
                float* __restrict__ idxf, int* __restrict__ flagn,
                int* __restrict__ flaglist) {
    int n = blockIdx.x * 256 + threadIdx.x;
    float v1 = candv[n], v2 = cand2v[n];
    int i1 = candi[n];
    #pragma unroll
    for (int jq = 1; jq < 8; ++jq) {
        float a1 = candv[(size_t)jq * BT + n];
        float a2 = cand2v[(size_t)jq * BT + n];
        int ai = candi[(size_t)jq * BT + n];
        if (a1 < v1 || (a1 == v1 && ai < i1)) {
            v2 = fminf(v1, a2); v1 = a1; i1 = ai;
        } else {
            v2 = fminf(v2, a1);
        }
    }
    idxI[n] = i1;
    idxf[n] = (float)i1;
    if (v2 - v1 < MARGIN) {
        int s = atomicAdd(flagn, 1);
        flaglist[s] = n;
    }
}

// ---------------------------------------------------------------------------
// vq_rescue: near-exact re-score of flagged positions over all 1024 codes.
// z reconstructed as hi+lo+lo2 (error <= 2^-27 |z| -- two orders below the
// scale that ever flipped an index).
// ---------------------------------------------------------------------------
__global__ __launch_bounds__(256)
void vq_rescue(const int* __restrict__ flagn, const int* __restrict__ flaglist,
               const unsigned short* __restrict__ Zt,
               const unsigned short* __restrict__ Lo2,
               const float* __restrict__ CB,
               const float* __restrict__ CN, int* __restrict__ idxI,
               float* __restrict__ idxf) {
    __shared__ float zs[512];
    __shared__ float rvv[256];
    __shared__ int   rii[256];
    const int nf = *flagn;
    for (int f = blockIdx.x; f < nf; f += gridDim.x) {
        int n = flaglist[f];
        __syncthreads();
        #pragma unroll
        for (int it = 0; it < 2; ++it) {
            int d = threadIdx.x + it * 256;
            const unsigned short* zr = Zt + ((size_t)n * 16 + (d >> 5)) * 64
                                       + (d & 31);
            zs[d] = bf2f(zr[0]) + bf2f(zr[32]) + bf2f(Lo2[(size_t)n * 512 + d]);
        }
        __syncthreads();
        float bv = 1e30f;
        int bi = 0;
        #pragma unroll
        for (int jj = 0; jj < 4; ++jj) {
            int j = threadIdx.x * 4 + jj;
            const float* cr = CB + (size_t)j * Dc;
            float dot = 0.f;
            for (int d = 0; d < Dc; ++d) dot = fmaf(zs[d], cr[d], dot);
            float dist = fmaf(-2.f, dot, CN[j]);
            if (dist < bv || (dist == bv && j < bi)) { bv = dist; bi = j; }
        }
        rvv[threadIdx.x] = bv;
        rii[threadIdx.x] = bi;
        __syncthreads();
        for (int off = 128; off > 0; off >>= 1) {
            if (threadIdx.x < off) {
                float ov = rvv[threadIdx.x + off];
                int oi = rii[threadIdx.x + off];
                if (ov < rvv[threadIdx.x] ||
                    (ov == rvv[threadIdx.x] && oi < rii[threadIdx.x])) {
                    rvv[threadIdx.x] = ov; rii[threadIdx.x] = oi;
                }
            }
            __syncthreads();
        }
        if (threadIdx.x == 0) {
            idxI[n] = rii[0];
            idxf[n] = (float)rii[0];
        }
    }
}

// ---------------------------------------------------------------------------
// gemm_g: G[j][kk*512+o] = sum_c CB[j][c] * dec_w1[o][c][kk].
// ---------------------------------------------------------------------------
__global__ __launch_bounds__(256)
void gemm_g(const float* __restrict__ CBt, const float* __restrict__ Wt,
            float* __restrict__ G) {
    const int j0 = blockIdx.x * 64;
    const int kk = blockIdx.y >> 2;
    const int o0 = (blockIdx.y & 3) * 128;
    __shared__ __align__(16) float As[16][68];
    __shared__ __align__(16) float Bs[16][132];
    const int tid = threadIdx.x;
    const int tx = tid & 15, ty = tid >> 4;
    float acc[4][8] = {};

    for (int c0 = 0; c0 < Dc; c0 += 16) {
        {
            int cc = tid >> 4, j4 = tid & 15;
            *(float4*)&As[cc][j4 * 4] =
                *(const float4*)&CBt[(size_t)(c0 + cc) * NCODE + j0 + j4 * 4];
        }
        #pragma unroll
        for (int it = 0; it < 2; ++it) {
            int i = tid + it * 256;
            int cc = i >> 5, o4 = i & 31;
            *(float4*)&Bs[cc][o4 * 4] =
                *(const float4*)&Wt[(size_t)((c0 + cc) * 3 + kk) * Hc + o0 + o4 * 4];
        }
        __syncthreads();
        #pragma unroll
        for (int cc = 0; cc < 16; ++cc) {
            float4 a = *(const float4*)&As[cc][tx * 4];
            float av[4] = {a.x, a.y, a.z, a.w};
            float4 b0 = *(const float4*)&Bs[cc][ty * 4];
            float4 b1 = *(const float4*)&Bs[cc][64 + ty * 4];
            float bv[8] = {b0.x, b0.y, b0.z, b0.w, b1.x, b1.y, b1.z, b1.w};
            #pragma unroll
            for (int jj = 0; jj < 4; ++jj)
                #pragma unroll
                for (int oo = 0; oo < 8; ++oo)
                    acc[jj][oo] = fmaf(av[jj], bv[oo], acc[jj][oo]);
        }
        __syncthreads();
    }
    #pragma unroll
    for (int jj = 0; jj < 4; ++jj) {
        int j = j0 + tx * 4 + jj;
        float* gp = G + (size_t)j * 1536 + kk * 512 + o0;
        *(float4*)(gp + ty * 4) = *(float4*)&acc[jj][0];
        *(float4*)(gp + 64 + ty * 4) = *(float4*)&acc[jj][4];
    }
}

// ---------------------------------------------------------------------------
// dec_y3: y3t[b][t][o] (bf16, rows of 512, guards folded in) =
//   f2bf(relu(b1[o] + sum_kk G[idx[b][t+kk-1]][kk*512+o])).
// ---------------------------------------------------------------------------
__global__ __launch_bounds__(256)
void dec_y3(const int* __restrict__ idx, const float* __restrict__ G,
            const float* __restrict__ bias, unsigned short* __restrict__ Yt) {
    const int t0 = blockIdx.x * 64;
    const int o0 = blockIdx.y * 128;
    const int b  = blockIdx.z;
    const int tid = threadIdx.x;
    __shared__ int sidx[66];
    __shared__ __align__(16) float Ys[128][68];

    // guard rows (t=-1 and t=Tn): zero this block's o-slice (128 ushorts)
    if (blockIdx.x == 0 && tid < 32) {
        u16x4 z4 = {0, 0, 0, 0};
        *(u16x4*)(Yt + (size_t)(b * (Tn + 2)) * 512 + o0 + tid * 4) = z4;
    }
    if (blockIdx.x == Tn / 64 - 1 && tid < 32) {
        u16x4 z4 = {0, 0, 0, 0};
        *(u16x4*)(Yt + (size_t)(b * (Tn + 2) + Tn + 1) * 512 + o0 + tid * 4) = z4;
    }

    if (tid < 66) {
        int t = t0 + tid - 1;
        sidx[tid] = (t >= 0 && t < Tn) ? idx[b * Tn + t] : -1;
    }
    __syncthreads();

    const int o = tid & 127;
    const int half = tid >> 7;
    float acc[32] = {};
    #pragma unroll
    for (int kk = 0; kk < 3; ++kk) {
        const float* Gk = G + (size_t)kk * 512 + o0 + o;
        #pragma unroll
        for (int k = 0; k < 32; ++k) {
            int j = sidx[half + 2 * k + kk];
            if (j >= 0) acc[k] += Gk[(size_t)j * 1536];
        }
    }
    float bv = bias[o0 + o];
    #pragma unroll
    for (int k = 0; k < 32; ++k)
        Ys[o][half + 2 * k] = fmaxf(acc[k] + bv, 0.f);
    __syncthreads();

    unsigned short* Yb = Yt + ((size_t)(b * (Tn + 2) + 1 + t0)) * 512 + o0;
    #pragma unroll
    for (int it = 0; it < 8; ++it) {
        int i = tid + it * 256;            // 2048 = 32 o-quads x 64 t
        int t = i >> 5, oq = i & 31;
        u16x4 h;
        #pragma unroll
        for (int r = 0; r < 4; ++r)
            h[r] = f2bf(Ys[oq * 4 + r][t]);
        *(u16x4*)(Yb + (size_t)t * 512 + oq * 4) = h;
    }
}

// ---------------------------------------------------------------------------
extern "C" void kernel_launch(void* const* d_in, const int* in_sizes, int n_in,
                              void* d_out, int out_size, void* d_ws, size_t ws_size,
                              hipStream_t stream) {
    const float* mels    = (const float*)d_in[0];
    const float* enc_w1  = (const float*)d_in[1];
    const float* enc_b1  = (const float*)d_in[2];
    const float* enc_w2  = (const float*)d_in[3];
    const float* enc_b2  = (const float*)d_in[4];
    const float* codebook= (const float*)d_in[5];
    const float* dec_w1  = (const float*)d_in[6];
    const float* dec_b1  = (const float*)d_in[7];
    const float* dec_w2  = (const float*)d_in[8];
    const float* dec_b2  = (const float*)d_in[9];

    float* out = (float*)d_out;
    float* recon = out;                 // [B,T,80]
    float* idxf  = out + RECON_N;       // [B,T] as float

    const size_t ACT = (size_t)Bsz * Hc * Tn;          // 16,777,216 floats
    const size_t Y1HL_U = (size_t)Bsz * (Tn + 2) * 1024 + 16384; // ushorts+slack
    const size_t R2F = Y1HL_U / 2;                      // floats

    // Region R1 (67 MB): Zt interleaved hi/lo (conv_mid out, vq+rescue read)
    //                    -> later y3t bf16 (dec path, after rescue)
    unsigned short* Zt  = (unsigned short*)d_ws;        // [BT*1024] ushorts
    unsigned short* y3t = (unsigned short*)d_ws;        // aliases Zt post-rescue
    // Region R2 (67 MB): y1hl interleaved (enc1 out, conv_mid in)
    float* r2 = (float*)d_ws + ACT;
    unsigned short* y1hl = (unsigned short*)r2;
    // small region
    float* sm    = r2 + R2F;
    int*   idxI  = (int*)sm;                            // [BT]
    float* cn    = (float*)(idxI + BT);                 // [NCODE]
    float* cbt   = cn + NCODE;                          // [Dc*NCODE]
    float* wt1   = cbt + (size_t)Dc * NCODE;            // enc_w1t: 80*3*512
    float* wt3   = wt1 + (size_t)INC * 3 * Hc;          // dec_w1t: 512*3*512
    float* candv = wt3 + (size_t)Dc * 3 * Hc;           // [8*BT]
    float* cand2v= candv + (size_t)8 * BT;              // [8*BT]
    int*   candi = (int*)(cand2v + (size_t)8 * BT);     // [8*BT]
    int*   flagn = candi + (size_t)8 * BT;              // [4]
    int*   flaglist = flagn + 4;                        // [BT]
    float* G     = (float*)(flaglist + BT);             // [NCODE*1536]
    unsigned short* whl  = (unsigned short*)(G + (size_t)NCODE * 1536); // [3*Hc*1024]
    unsigned short* cbhl = whl + (size_t)3 * Hc * 1024;                 // [NCODE*1024]
    unsigned short* wh2  = cbhl + (size_t)NCODE * 1024;                 // [3*INC*Hc]
    float* melsT = (float*)(wh2 + (size_t)3 * INC * Hc);                // [B,80,T]
    // lo2 residual plane [BT*512] ushorts; aliases melsT (dead after enc1)
    // and extends past it -- written by conv_mid, read by vq_rescue.
    unsigned short* lo2 = (unsigned short*)melsT;

    dim3 blk(256);
    hipMemsetAsync(flagn, 0, 16, stream);
    // prep: norms + transposes + bf16 splits
    code_norms<<<dim3(NCODE), dim3(64), 0, stream>>>(codebook, cn);
    cb_transpose<<<dim3(NCODE / 64, Dc / 64), blk, 0, stream>>>(codebook, cbt);
    mels_transpose<<<dim3(Tn / 64, Bsz), blk, 0, stream>>>(mels, melsT);
    wt_transpose<<<dim3(Hc / 64, INC / 16), blk, 0, stream>>>(enc_w1, wt1, INC, Hc);
    wsplit<<<dim3(Hc, 3), blk, 0, stream>>>(enc_w2, whl);
    cbsplit<<<dim3(NCODE), blk, 0, stream>>>(codebook, cbhl);
    wt_transpose<<<dim3(Hc / 64, Dc / 16), blk, 0, stream>>>(dec_w1, wt3, Dc, Hc);
    wsplit80<<<dim3(INC, 3), blk, 0, stream>>>(dec_w2, wh2);
    // decoder conv1 folded matrix (independent of activations)
    gemm_g<<<dim3(NCODE / 64, 12), blk, 0, stream>>>(cbt, wt3, G);
    // encoder (enc1 writes interleaved y1hl + its guard rows)
    conv_enc1<<<dim3(Tn / 64, Hc / 128, Bsz), blk, 0, stream>>>(melsT, wt1, enc_b1,
                                                                y1hl);
    // conv_mid writes Zt (hi/lo) + lo2 residual directly; split_t eliminated
    conv_mid_mfma<<<dim3(Tn / 128, Hc / 128, Bsz), blk, 0, stream>>>(y1hl, whl,
                                                                     enc_b2,
                                                                     Zt, lo2);
    // vector quantization: MFMA approx + margin-guarded near-exact rescue
    vq_mfma<<<dim3(BT / 128, NCODE / 128), blk, 0, stream>>>(Zt, cbhl, cn,
                                                             candv, candi, cand2v);
    vq_reduce2<<<dim3(BT / 256), blk, 0, stream>>>(candv, candi, cand2v, idxI,
                                                   idxf, flagn, flaglist);
    vq_rescue<<<dim3(128), blk, 0, stream>>>(flagn, flaglist, Zt, lo2, codebook,
                                             cn, idxI, idxf);
    // decoder: conv1 via gather of G rows (bf16 out + guards), conv2 via MFMA
    dec_y3<<<dim3(Tn / 64, 4, Bsz), blk, 0, stream>>>(idxI, G, dec_b1, y3t);
    dec2_mfma<<<dim3(Tn / 128, 1, Bsz), blk, 0, stream>>>(y3t, wh2, dec_b2, recon);
}